// Round 1
// baseline (1622.087 us; speedup 1.0000x reference)
//
#include <hip/hip_runtime.h>
#include <cstddef>

// Problem constants
#define Bsz 8
#define Nn  1024
#define Cc  512
#define Hh  8
#define Dd  64
#define QKV_LD 1536
#define EPSF 1e-6f

// ---------------------------------------------------------------------------
// Generic tiled fp32 GEMM: out[M][NC] = A[M][K] @ W[K][NC]
// Optional bias add; relu+eps applied to columns < reluCols.
// 64x64 tile, K-step 16, 256 threads, 4x4 micro-tile per thread.
// ---------------------------------------------------------------------------
__global__ __launch_bounds__(256)
void gemm_k(const float* __restrict__ A, const float* __restrict__ W,
            const float* __restrict__ bias, float* __restrict__ out,
            int M, int K, int NC, int reluCols) {
    __shared__ float As[64][17];   // [m][k], padded (+1) to avoid bank conflicts
    __shared__ float Ws[16][64];   // [k][n]

    const int tid = threadIdx.x;
    const int tx = tid % 16;       // n-group
    const int ty = tid / 16;       // m-group
    const int m0 = blockIdx.y * 64;
    const int n0 = blockIdx.x * 64;

    float acc[4][4] = {};

    for (int k0 = 0; k0 < K; k0 += 16) {
        // A tile: 64x16 = 1024 elems, 4 per thread
        #pragma unroll
        for (int i = 0; i < 4; i++) {
            int idx = tid + i * 256;
            int r = idx / 16, c = idx % 16;
            As[r][c] = A[(size_t)(m0 + r) * K + k0 + c];
        }
        // W tile: 16x64
        #pragma unroll
        for (int i = 0; i < 4; i++) {
            int idx = tid + i * 256;
            int r = idx / 64, c = idx % 64;
            Ws[r][c] = W[(size_t)(k0 + r) * NC + n0 + c];
        }
        __syncthreads();
        #pragma unroll
        for (int kk = 0; kk < 16; kk++) {
            float a[4], bv[4];
            #pragma unroll
            for (int i = 0; i < 4; i++) a[i] = As[ty * 4 + i][kk];
            #pragma unroll
            for (int j = 0; j < 4; j++) bv[j] = Ws[kk][tx * 4 + j];
            #pragma unroll
            for (int i = 0; i < 4; i++)
                #pragma unroll
                for (int j = 0; j < 4; j++)
                    acc[i][j] += a[i] * bv[j];
        }
        __syncthreads();
    }

    #pragma unroll
    for (int i = 0; i < 4; i++) {
        int m = m0 + ty * 4 + i;
        #pragma unroll
        for (int j = 0; j < 4; j++) {
            int n = n0 + tx * 4 + j;
            float v = acc[i][j];
            if (bias) v += bias[n];
            if (n < reluCols) v = fmaxf(v, 0.0f) + EPSF;
            out[(size_t)m * NC + n] = v;
        }
    }
}

// ---------------------------------------------------------------------------
// Graph diffusion: for batch b, part p (0=q,1=k):
//   dst[n][c] = src[n][c] + 0.1 * sum_m mask[m][n] * src[m][c]
// src = qkv[b][:][p*512 : p*512+512] (already relu+eps from gemm stage).
// GEMM with A[n][m] = mask[m][n] (transposed load into padded LDS).
// ---------------------------------------------------------------------------
__global__ __launch_bounds__(256)
void diffusion_k(const float* __restrict__ qkv, const float* __restrict__ mask,
                 float* __restrict__ qd, float* __restrict__ kd) {
    const int bz = blockIdx.z;
    const int b = bz >> 1;
    const int which = bz & 1;             // 0 -> q, 1 -> k
    const int coff = which ? Cc : 0;
    const float* src = qkv + (size_t)b * Nn * QKV_LD + coff;  // [m][c] stride QKV_LD
    float* dst = (which ? kd : qd) + (size_t)b * Nn * Cc;

    const int n0 = blockIdx.y * 64;
    const int c0 = blockIdx.x * 64;

    __shared__ float As[64][17];   // As[n][m_local] = mask[m0+m_local][n0+n]
    __shared__ float Bs[16][64];   // Bs[m_local][c]

    const int tid = threadIdx.x;
    const int tx = tid % 16;
    const int ty = tid / 16;

    float acc[4][4] = {};

    for (int m0 = 0; m0 < Nn; m0 += 16) {
        // mask tile 16x64, stored transposed
        #pragma unroll
        for (int i = 0; i < 4; i++) {
            int idx = tid + i * 256;
            int mi = idx / 64, nj = idx % 64;
            As[nj][mi] = mask[(size_t)(m0 + mi) * Nn + n0 + nj];
        }
        #pragma unroll
        for (int i = 0; i < 4; i++) {
            int idx = tid + i * 256;
            int mi = idx / 64, cj = idx % 64;
            Bs[mi][cj] = src[(size_t)(m0 + mi) * QKV_LD + c0 + cj];
        }
        __syncthreads();
        #pragma unroll
        for (int kk = 0; kk < 16; kk++) {
            float a[4], bv[4];
            #pragma unroll
            for (int i = 0; i < 4; i++) a[i] = As[ty * 4 + i][kk];
            #pragma unroll
            for (int j = 0; j < 4; j++) bv[j] = Bs[kk][tx * 4 + j];
            #pragma unroll
            for (int i = 0; i < 4; i++)
                #pragma unroll
                for (int j = 0; j < 4; j++)
                    acc[i][j] += a[i] * bv[j];
        }
        __syncthreads();
    }

    #pragma unroll
    for (int i = 0; i < 4; i++) {
        int n = n0 + ty * 4 + i;
        #pragma unroll
        for (int j = 0; j < 4; j++) {
            int c = c0 + tx * 4 + j;
            float base = src[(size_t)n * QKV_LD + c];
            dst[(size_t)n * Cc + c] = base + 0.1f * acc[i][j];
        }
    }
}

// ---------------------------------------------------------------------------
// Masked linear attention, flash-style (kernel matrix never materialized):
// per (b,h): S[n][m] = (q'[n] . k'[m]) * mask[n][m]
//            denom[n] = sum_m S[n][m];  num[n][d] = sum_m S[n][m] * v[m][d]
//            out[n][d] = num[n][d] / (denom[n] + eps)
// Block: 32 q-rows of one (b,h); loop over 32-wide m tiles.
// ---------------------------------------------------------------------------
__global__ __launch_bounds__(256)
void attn_k(const float* __restrict__ qkv, const float* __restrict__ qd,
            const float* __restrict__ kd, const float* __restrict__ mask,
            float* __restrict__ attnout) {
    const int bh = blockIdx.y;
    const int b = bh / Hh, h = bh % Hh;
    const int n0 = blockIdx.x * 32;

    const float* Q  = qd  + (size_t)b * Nn * Cc + h * Dd;            // stride Cc
    const float* Kp = kd  + (size_t)b * Nn * Cc + h * Dd;            // stride Cc
    const float* V  = qkv + (size_t)b * Nn * QKV_LD + 2 * Cc + h * Dd; // stride QKV_LD

    __shared__ float qs[32][65];
    __shared__ float ks[32][65];
    __shared__ float vs[32][64];
    __shared__ float ms[32][33];
    __shared__ float ss[32][33];
    __shared__ float dsh[32];

    const int tid = threadIdx.x;

    // load q tile once: 32x64
    #pragma unroll
    for (int i = 0; i < 8; i++) {
        int idx = tid + i * 256;
        int r = idx / 64, d = idx % 64;
        qs[r][d] = Q[(size_t)(n0 + r) * Cc + d];
    }

    float num[8] = {};
    float denom = 0.0f;    // valid for tid < 32, q-row tid

    // phase-2 ownership: fixed d = tid%64, rows nqb..nqb+7
    const int d2  = tid % 64;
    const int nqb = (tid / 64) * 8;
    // phase-1 ownership: row nq1, 4 consecutive m
    const int nq1 = tid / 8;
    const int mb1 = (tid % 8) * 4;

    for (int m0 = 0; m0 < Nn; m0 += 32) {
        __syncthreads();   // previous iter's ss/vs reads done (also covers qs load)
        // K,V tiles 32x64
        #pragma unroll
        for (int i = 0; i < 8; i++) {
            int idx = tid + i * 256;
            int r = idx / 64, d = idx % 64;
            ks[r][d] = Kp[(size_t)(m0 + r) * Cc + d];
            vs[r][d] = V[(size_t)(m0 + r) * QKV_LD + d];
        }
        // mask tile 32x32
        #pragma unroll
        for (int i = 0; i < 4; i++) {
            int idx = tid + i * 256;
            int r = idx / 32, c = idx % 32;
            ms[r][c] = mask[(size_t)(n0 + r) * Nn + m0 + c];
        }
        __syncthreads();

        // phase 1: scores
        {
            float s0 = 0.f, s1 = 0.f, s2 = 0.f, s3 = 0.f;
            #pragma unroll
            for (int d = 0; d < 64; d++) {
                float qv = qs[nq1][d];
                s0 += qv * ks[mb1 + 0][d];
                s1 += qv * ks[mb1 + 1][d];
                s2 += qv * ks[mb1 + 2][d];
                s3 += qv * ks[mb1 + 3][d];
            }
            ss[nq1][mb1 + 0] = s0 * ms[nq1][mb1 + 0];
            ss[nq1][mb1 + 1] = s1 * ms[nq1][mb1 + 1];
            ss[nq1][mb1 + 2] = s2 * ms[nq1][mb1 + 2];
            ss[nq1][mb1 + 3] = s3 * ms[nq1][mb1 + 3];
        }
        __syncthreads();

        // phase 2: num += S @ V ; denom += rowsum(S)
        #pragma unroll
        for (int m = 0; m < 32; m++) {
            float vv = vs[m][d2];
            #pragma unroll
            for (int i = 0; i < 8; i++) {
                num[i] += ss[nqb + i][m] * vv;
            }
        }
        if (tid < 32) {
            float dsum = 0.f;
            #pragma unroll
            for (int m = 0; m < 32; m++) dsum += ss[tid][m];
            denom += dsum;
        }
    }

    __syncthreads();
    if (tid < 32) dsh[tid] = denom;
    __syncthreads();

    float* dst = attnout + (size_t)b * Nn * Cc + h * Dd;
    #pragma unroll
    for (int i = 0; i < 8; i++) {
        int nq = nqb + i;
        float z = 1.0f / (dsh[nq] + EPSF);
        dst[(size_t)(n0 + nq) * Cc + d2] = num[i] * z;
    }
}

// ---------------------------------------------------------------------------
extern "C" void kernel_launch(void* const* d_in, const int* in_sizes, int n_in,
                              void* d_out, int out_size, void* d_ws, size_t ws_size,
                              hipStream_t stream) {
    const float* x     = (const float*)d_in[0];   // [B,N,C]
    const float* mask  = (const float*)d_in[1];   // [N,N]
    const float* w_qkv = (const float*)d_in[2];   // [C,3C]
    const float* w_out = (const float*)d_in[3];   // [C,C]
    const float* b_out = (const float*)d_in[4];   // [C]
    float* out = (float*)d_out;                   // [B,N,C]

    float* ws   = (float*)d_ws;
    float* qkv  = ws;                                    // B*N*3C = 12,582,912 f
    float* qd   = qkv + (size_t)Bsz * Nn * QKV_LD;       // B*N*C  =  4,194,304 f
    float* kd   = qd  + (size_t)Bsz * Nn * Cc;
    float* attn = kd  + (size_t)Bsz * Nn * Cc;           // total ~101 MB

    dim3 blk(256);

    // 1) qkv projection + relu+eps on q,k thirds
    gemm_k<<<dim3(QKV_LD / 64, (Bsz * Nn) / 64), blk, 0, stream>>>(
        x, w_qkv, nullptr, qkv, Bsz * Nn, Cc, QKV_LD, 2 * Cc);

    // 2) graph diffusion for q and k
    diffusion_k<<<dim3(Cc / 64, Nn / 64, Bsz * 2), blk, 0, stream>>>(
        qkv, mask, qd, kd);

    // 3) masked linear attention
    attn_k<<<dim3(Nn / 32, Bsz * Hh), blk, 0, stream>>>(
        qkv, qd, kd, mask, attn);

    // 4) output projection + bias
    gemm_k<<<dim3(Cc / 64, (Bsz * Nn) / 64), blk, 0, stream>>>(
        attn, w_out, b_out, out, Bsz * Nn, Cc, Cc, 0);
}

// Round 2
// 647.293 us; speedup vs baseline: 2.5060x; 2.5060x over previous
//
#include <hip/hip_runtime.h>
#include <cstddef>

// Problem constants
#define Bsz 8
#define Nn  1024
#define Cc  512
#define Hh  8
#define Dd  64
#define QKV_LD 1536
#define EPSF 1e-6f

typedef __attribute__((ext_vector_type(8))) short short8;   // 8 bf16 (4 VGPRs)
typedef __attribute__((ext_vector_type(4))) float floatx4;  // MFMA accumulator

// round-to-nearest-even fp32 -> bf16 (bit pattern in a short)
static __device__ __forceinline__ short f2bf(float f) {
    union { float f; unsigned u; } v; v.f = f;
    unsigned r = (v.u + 0x7FFFu + ((v.u >> 16) & 1u)) >> 16;
    return (short)r;
}

// ---------------------------------------------------------------------------
// Generic tiled fp32 GEMM: out[M][NC] = A[M][K] @ W[K][NC]
// Optional bias add; relu+eps applied to columns < reluCols.
// ---------------------------------------------------------------------------
__global__ __launch_bounds__(256)
void gemm_k(const float* __restrict__ A, const float* __restrict__ W,
            const float* __restrict__ bias, float* __restrict__ out,
            int M, int K, int NC, int reluCols) {
    __shared__ float As[64][17];
    __shared__ float Ws[16][64];

    const int tid = threadIdx.x;
    const int tx = tid % 16;
    const int ty = tid / 16;
    const int m0 = blockIdx.y * 64;
    const int n0 = blockIdx.x * 64;

    float acc[4][4] = {};

    for (int k0 = 0; k0 < K; k0 += 16) {
        #pragma unroll
        for (int i = 0; i < 4; i++) {
            int idx = tid + i * 256;
            int r = idx / 16, c = idx % 16;
            As[r][c] = A[(size_t)(m0 + r) * K + k0 + c];
        }
        #pragma unroll
        for (int i = 0; i < 4; i++) {
            int idx = tid + i * 256;
            int r = idx / 64, c = idx % 64;
            Ws[r][c] = W[(size_t)(k0 + r) * NC + n0 + c];
        }
        __syncthreads();
        #pragma unroll
        for (int kk = 0; kk < 16; kk++) {
            float a[4], bv[4];
            #pragma unroll
            for (int i = 0; i < 4; i++) a[i] = As[ty * 4 + i][kk];
            #pragma unroll
            for (int j = 0; j < 4; j++) bv[j] = Ws[kk][tx * 4 + j];
            #pragma unroll
            for (int i = 0; i < 4; i++)
                #pragma unroll
                for (int j = 0; j < 4; j++)
                    acc[i][j] += a[i] * bv[j];
        }
        __syncthreads();
    }

    #pragma unroll
    for (int i = 0; i < 4; i++) {
        int m = m0 + ty * 4 + i;
        #pragma unroll
        for (int j = 0; j < 4; j++) {
            int n = n0 + tx * 4 + j;
            float v = acc[i][j];
            if (bias) v += bias[n];
            if (n < reluCols) v = fmaxf(v, 0.0f) + EPSF;
            out[(size_t)m * NC + n] = v;
        }
    }
}

// ---------------------------------------------------------------------------
// Graph diffusion: dst[n][c] = src[n][c] + 0.1 * sum_m mask[m][n] * src[m][c]
// ---------------------------------------------------------------------------
__global__ __launch_bounds__(256)
void diffusion_k(const float* __restrict__ qkv, const float* __restrict__ mask,
                 float* __restrict__ qd, float* __restrict__ kd) {
    const int bz = blockIdx.z;
    const int b = bz >> 1;
    const int which = bz & 1;
    const int coff = which ? Cc : 0;
    const float* src = qkv + (size_t)b * Nn * QKV_LD + coff;
    float* dst = (which ? kd : qd) + (size_t)b * Nn * Cc;

    const int n0 = blockIdx.y * 64;
    const int c0 = blockIdx.x * 64;

    __shared__ float As[64][17];
    __shared__ float Bs[16][64];

    const int tid = threadIdx.x;
    const int tx = tid % 16;
    const int ty = tid / 16;

    float acc[4][4] = {};

    for (int m0 = 0; m0 < Nn; m0 += 16) {
        #pragma unroll
        for (int i = 0; i < 4; i++) {
            int idx = tid + i * 256;
            int mi = idx / 64, nj = idx % 64;
            As[nj][mi] = mask[(size_t)(m0 + mi) * Nn + n0 + nj];
        }
        #pragma unroll
        for (int i = 0; i < 4; i++) {
            int idx = tid + i * 256;
            int mi = idx / 64, cj = idx % 64;
            Bs[mi][cj] = src[(size_t)(m0 + mi) * QKV_LD + c0 + cj];
        }
        __syncthreads();
        #pragma unroll
        for (int kk = 0; kk < 16; kk++) {
            float a[4], bv[4];
            #pragma unroll
            for (int i = 0; i < 4; i++) a[i] = As[ty * 4 + i][kk];
            #pragma unroll
            for (int j = 0; j < 4; j++) bv[j] = Bs[kk][tx * 4 + j];
            #pragma unroll
            for (int i = 0; i < 4; i++)
                #pragma unroll
                for (int j = 0; j < 4; j++)
                    acc[i][j] += a[i] * bv[j];
        }
        __syncthreads();
    }

    #pragma unroll
    for (int i = 0; i < 4; i++) {
        int n = n0 + ty * 4 + i;
        #pragma unroll
        for (int j = 0; j < 4; j++) {
            int c = c0 + tx * 4 + j;
            float base = src[(size_t)n * QKV_LD + c];
            dst[(size_t)n * Cc + c] = base + 0.1f * acc[i][j];
        }
    }
}

// ---------------------------------------------------------------------------
// Masked linear attention via MFMA bf16, flash-style.
// Block = one (b,h), 64 q-rows; loop over 64-wide m chunks.
// Wave w owns q-rows [16w, 16w+16).  S computed in fp32 (mask multiply
// exact on the accumulator), rounded to bf16 only as the PV A-operand.
// ---------------------------------------------------------------------------
#define LDQ 72   // bf16 elements per LDS row (144 B; staggers banks)
#define LDM 68   // fp32 elements per mask LDS row (272 B; keeps 16B align)

__global__ __launch_bounds__(256)
void attn_mfma(const float* __restrict__ qkv, const float* __restrict__ qd,
               const float* __restrict__ kd, const float* __restrict__ mask,
               float* __restrict__ attnout) {
    __shared__ short qs[64 * LDQ];
    __shared__ short ks[64 * LDQ];
    __shared__ short vt[64 * LDQ];   // V transposed: vt[d][m]
    __shared__ short ss[64 * LDQ];   // masked S, bf16 (PV A-operand)
    __shared__ float ms[64 * LDM];   // mask tile fp32

    const int tid  = threadIdx.x;
    const int bh   = blockIdx.y;
    const int b    = bh >> 3, h = bh & 7;
    const int n0   = blockIdx.x * 64;

    const float* Q  = qd  + (size_t)b * Nn * Cc + h * Dd;              // stride Cc
    const float* Kp = kd  + (size_t)b * Nn * Cc + h * Dd;              // stride Cc
    const float* V  = qkv + (size_t)b * Nn * QKV_LD + 2 * Cc + h * Dd; // stride QKV_LD

    const int wave = tid >> 6;
    const int lane = tid & 63;
    const int quad = lane >> 4;
    const int l16  = lane & 15;

    // stage Q once: 64x64 fp32 -> bf16
    #pragma unroll
    for (int i = 0; i < 4; i++) {
        int idx = tid + i * 256;
        int r = idx >> 4, c4 = (idx & 15) << 2;
        float4 q4 = *(const float4*)&Q[(size_t)(n0 + r) * Cc + c4];
        short* d = &qs[r * LDQ + c4];
        d[0] = f2bf(q4.x); d[1] = f2bf(q4.y); d[2] = f2bf(q4.z); d[3] = f2bf(q4.w);
    }

    float  dreg[4] = {0.f, 0.f, 0.f, 0.f};
    floatx4 nacc[4];
    #pragma unroll
    for (int i = 0; i < 4; i++) nacc[i] = (floatx4){0.f, 0.f, 0.f, 0.f};

    for (int m0 = 0; m0 < Nn; m0 += 64) {
        __syncthreads();   // prior chunk's readers done (also orders qs staging)
        // stage K, V^T (bf16), mask (fp32)
        #pragma unroll
        for (int i = 0; i < 4; i++) {
            int idx = tid + i * 256;
            int r = idx >> 4, c4 = (idx & 15) << 2;
            float4 k4 = *(const float4*)&Kp[(size_t)(m0 + r) * Cc + c4];
            short* d = &ks[r * LDQ + c4];
            d[0] = f2bf(k4.x); d[1] = f2bf(k4.y); d[2] = f2bf(k4.z); d[3] = f2bf(k4.w);
            float4 v4 = *(const float4*)&V[(size_t)(m0 + r) * QKV_LD + c4];
            vt[(c4 + 0) * LDQ + r] = f2bf(v4.x);
            vt[(c4 + 1) * LDQ + r] = f2bf(v4.y);
            vt[(c4 + 2) * LDQ + r] = f2bf(v4.z);
            vt[(c4 + 3) * LDQ + r] = f2bf(v4.w);
            float4 m4 = *(const float4*)&mask[(size_t)(n0 + r) * Nn + m0 + c4];
            *(float4*)&ms[r * LDM + c4] = m4;
        }
        __syncthreads();

        // ---- phase A: S = (Q K^T) * mask  (fp32), -> ss (bf16), denom acc
        const short8 a0 = *(const short8*)&qs[(wave * 16 + l16) * LDQ + 0  + quad * 8];
        const short8 a1 = *(const short8*)&qs[(wave * 16 + l16) * LDQ + 32 + quad * 8];
        #pragma unroll
        for (int mt = 0; mt < 4; mt++) {
            const short8 b0 = *(const short8*)&ks[(mt * 16 + l16) * LDQ + 0  + quad * 8];
            const short8 b1 = *(const short8*)&ks[(mt * 16 + l16) * LDQ + 32 + quad * 8];
            floatx4 s = (floatx4){0.f, 0.f, 0.f, 0.f};
            s = __builtin_amdgcn_mfma_f32_16x16x32_bf16(a0, b0, s, 0, 0, 0);
            s = __builtin_amdgcn_mfma_f32_16x16x32_bf16(a1, b1, s, 0, 0, 0);
            #pragma unroll
            for (int r = 0; r < 4; r++) {
                int rl = wave * 16 + quad * 4 + r;   // C-layout: row = quad*4+reg
                float sv = s[r] * ms[rl * LDM + mt * 16 + l16];
                dreg[r] += sv;
                ss[rl * LDQ + mt * 16 + l16] = f2bf(sv);
            }
        }
        __syncthreads();

        // ---- phase B: num += S @ V  (A-frags from ss, B-frags from vt)
        const short8 p0 = *(const short8*)&ss[(wave * 16 + l16) * LDQ + 0  + quad * 8];
        const short8 p1 = *(const short8*)&ss[(wave * 16 + l16) * LDQ + 32 + quad * 8];
        #pragma unroll
        for (int dt = 0; dt < 4; dt++) {
            const short8 v0 = *(const short8*)&vt[(dt * 16 + l16) * LDQ + 0  + quad * 8];
            const short8 v1 = *(const short8*)&vt[(dt * 16 + l16) * LDQ + 32 + quad * 8];
            nacc[dt] = __builtin_amdgcn_mfma_f32_16x16x32_bf16(p0, v0, nacc[dt], 0, 0, 0);
            nacc[dt] = __builtin_amdgcn_mfma_f32_16x16x32_bf16(p1, v1, nacc[dt], 0, 0, 0);
        }
    }

    // denom: reduce across the 16 lanes of each quad (xor bits 0..3)
    #pragma unroll
    for (int r = 0; r < 4; r++) {
        #pragma unroll
        for (int off = 1; off < 16; off <<= 1)
            dreg[r] += __shfl_xor(dreg[r], off, 64);
    }

    float* O = attnout + (size_t)b * Nn * Cc + h * Dd;
    #pragma unroll
    for (int r = 0; r < 4; r++) {
        int n = n0 + wave * 16 + quad * 4 + r;
        float z = 1.0f / (dreg[r] + EPSF);
        #pragma unroll
        for (int dt = 0; dt < 4; dt++)
            O[(size_t)n * Cc + dt * 16 + l16] = nacc[dt][r] * z;
    }
}

// ---------------------------------------------------------------------------
extern "C" void kernel_launch(void* const* d_in, const int* in_sizes, int n_in,
                              void* d_out, int out_size, void* d_ws, size_t ws_size,
                              hipStream_t stream) {
    const float* x     = (const float*)d_in[0];
    const float* mask  = (const float*)d_in[1];
    const float* w_qkv = (const float*)d_in[2];
    const float* w_out = (const float*)d_in[3];
    const float* b_out = (const float*)d_in[4];
    float* out = (float*)d_out;

    float* ws   = (float*)d_ws;
    float* qkv  = ws;
    float* qd   = qkv + (size_t)Bsz * Nn * QKV_LD;
    float* kd   = qd  + (size_t)Bsz * Nn * Cc;
    float* attn = kd  + (size_t)Bsz * Nn * Cc;

    dim3 blk(256);

    gemm_k<<<dim3(QKV_LD / 64, (Bsz * Nn) / 64), blk, 0, stream>>>(
        x, w_qkv, nullptr, qkv, Bsz * Nn, Cc, QKV_LD, 2 * Cc);

    diffusion_k<<<dim3(Cc / 64, Nn / 64, Bsz * 2), blk, 0, stream>>>(
        qkv, mask, qd, kd);

    attn_mfma<<<dim3(Nn / 64, Bsz * Hh), blk, 0, stream>>>(
        qkv, qd, kd, mask, attn);

    gemm_k<<<dim3(Cc / 64, (Bsz * Nn) / 64), blk, 0, stream>>>(
        attn, w_out, b_out, out, Bsz * Nn, Cc, Cc, 0);
}

// Round 4
// 223.031 us; speedup vs baseline: 7.2729x; 2.9023x over previous
//
#include <hip/hip_runtime.h>
#include <cstddef>

// Problem constants
#define Bsz 8
#define Nn  1024
#define Cc  512
#define Hh  8
#define Dd  64
#define EPSF 1e-6f

typedef __attribute__((ext_vector_type(8))) short short8;   // 8 bf16 (4 VGPRs)
typedef __attribute__((ext_vector_type(4))) float floatx4;  // MFMA accumulator

// round-to-nearest-even fp32 -> bf16 (bit pattern in a short)
static __device__ __forceinline__ short f2bf(float f) {
    union { float f; unsigned u; } v; v.f = f;
    unsigned r = (v.u + 0x7FFFu + ((v.u >> 16) & 1u)) >> 16;
    return (short)r;
}
static __device__ __forceinline__ float bf2f(short s) {
    union { unsigned u; float f; } v; v.u = ((unsigned)(unsigned short)s) << 16;
    return v.f;
}

// ---------------------------------------------------------------------------
// Swizzled staging: 128 rows x 64 bf16 tile into LDS, linear 16B slots.
// Slot s holds row r=s/8, global chunk (s%8)^(r%8).  Frag read for row r,
// logical chunk lc is at slot r*8 + (lc^(r%8)) -> bank-balanced b128 reads.
// ---------------------------------------------------------------------------
static __device__ __forceinline__
void stage128x64(short* __restrict__ lds, const short* __restrict__ src,
                 int ldsrc, int tid) {
    #pragma unroll
    for (int i = 0; i < 4; i++) {
        int s = i * 256 + tid;
        int r = s >> 3, cs = s & 7;
        int gc = cs ^ (r & 7);
        *(int4*)&lds[s * 8] = *(const int4*)&src[(size_t)r * ldsrc + gc * 8];
    }
}
static __device__ __forceinline__
short8 frag64(const short* __restrict__ lds, int r, int lc) {
    return *(const short8*)&lds[(r * 8 + (lc ^ (r & 7))) * 8];
}

// ---------------------------------------------------------------------------
// prep kernels (all cheap, run once per launch)
// ---------------------------------------------------------------------------
__global__ __launch_bounds__(256)
void prep_x(const float* __restrict__ x, short* __restrict__ xb) {
    int idx = blockIdx.x * 256 + threadIdx.x;          // 8 elems per thread
    const float* s = &x[(size_t)idx * 8];
    union { short h[8]; int4 v; } u;
    #pragma unroll
    for (int j = 0; j < 8; j++) u.h[j] = f2bf(s[j]);
    *(int4*)&xb[(size_t)idx * 8] = u.v;
}

// Ad[n][m] = bf16( (n==m) + 0.1*mask[m][n] )
__global__ __launch_bounds__(256)
void prep_adiff(const float* __restrict__ mask, short* __restrict__ Ad) {
    __shared__ float t[64][65];
    const int tid = threadIdx.x;
    const int m0 = blockIdx.y * 64, n0 = blockIdx.x * 64;
    #pragma unroll
    for (int i = 0; i < 4; i++) {
        int idx = i * 256 + tid;
        int r = idx >> 4, c4 = (idx & 15) * 4;
        *(float4*)&t[r][c4] = *(const float4*)&mask[(size_t)(m0 + r) * Nn + n0 + c4];
    }
    __syncthreads();
    #pragma unroll
    for (int i = 0; i < 4; i++) {
        int idx = i * 256 + tid;
        int rr = idx >> 4, c4 = (idx & 15) * 4;    // rr = n-local, c4 = m-local
        union { short h[4]; int2 v; } u;
        #pragma unroll
        for (int j = 0; j < 4; j++) {
            int mm = c4 + j;
            float v = 0.1f * t[mm][rr] + ((n0 + rr) == (m0 + mm) ? 1.0f : 0.0f);
            u.h[j] = f2bf(v);
        }
        *(int2*)&Ad[(size_t)(n0 + rr) * Nn + m0 + c4] = u.v;
    }
}

// wqT[n][k] = bf16(w_qkv[k][n])   w: [512][1536]
__global__ __launch_bounds__(256)
void prep_wq(const float* __restrict__ w, short* __restrict__ wqT) {
    __shared__ float t[64][65];
    const int tid = threadIdx.x;
    const int k0 = blockIdx.y * 64, n0 = blockIdx.x * 64;
    #pragma unroll
    for (int i = 0; i < 4; i++) {
        int idx = i * 256 + tid;
        int r = idx >> 4, c4 = (idx & 15) * 4;
        *(float4*)&t[r][c4] = *(const float4*)&w[(size_t)(k0 + r) * 1536 + n0 + c4];
    }
    __syncthreads();
    #pragma unroll
    for (int i = 0; i < 4; i++) {
        int idx = i * 256 + tid;
        int rr = idx >> 4, c4 = (idx & 15) * 4;
        union { short h[4]; int2 v; } u;
        #pragma unroll
        for (int j = 0; j < 4; j++) u.h[j] = f2bf(t[c4 + j][rr]);
        *(int2*)&wqT[(size_t)(n0 + rr) * 512 + k0 + c4] = u.v;
    }
}

// woT hi/lo [n][k] from w_out [512][512]
__global__ __launch_bounds__(256)
void prep_wo(const float* __restrict__ w, short* __restrict__ whi,
             short* __restrict__ wlo) {
    __shared__ float t[64][65];
    const int tid = threadIdx.x;
    const int k0 = blockIdx.y * 64, n0 = blockIdx.x * 64;
    #pragma unroll
    for (int i = 0; i < 4; i++) {
        int idx = i * 256 + tid;
        int r = idx >> 4, c4 = (idx & 15) * 4;
        *(float4*)&t[r][c4] = *(const float4*)&w[(size_t)(k0 + r) * 512 + n0 + c4];
    }
    __syncthreads();
    #pragma unroll
    for (int i = 0; i < 4; i++) {
        int idx = i * 256 + tid;
        int rr = idx >> 4, c4 = (idx & 15) * 4;
        union { short h[4]; int2 v; } uh, ul;
        #pragma unroll
        for (int j = 0; j < 4; j++) {
            float v = t[c4 + j][rr];
            short hi = f2bf(v);
            uh.h[j] = hi;
            ul.h[j] = f2bf(v - bf2f(hi));
        }
        *(int2*)&whi[(size_t)(n0 + rr) * 512 + k0 + c4] = uh.v;
        *(int2*)&wlo[(size_t)(n0 + rr) * 512 + k0 + c4] = ul.v;
    }
}

// ---------------------------------------------------------------------------
// GEMM1: qkv = xb[8192][512] @ wqT^T, relu+eps on cols<1024.
// Epilogue: LDS transpose, writes qT/kT/vT[b][c][m] bf16 (B-operand layout).
// ---------------------------------------------------------------------------
__global__ __launch_bounds__(256)
void gemm_qkv(const short* __restrict__ xb, const short* __restrict__ wqT,
              short* __restrict__ qT, short* __restrict__ kT,
              short* __restrict__ vT) {
    __shared__ short smem[17408];             // 34816 B
    short* As = smem;                         // [128][64] swizzled
    short* Bs = smem + 8192;

    const int tid = threadIdx.x;
    const int m0 = blockIdx.y * 128;
    const int n0 = blockIdx.x * 128;
    const int wave = tid >> 6, lane = tid & 63;
    const int quad = lane >> 4, l16 = lane & 15;
    const int wm = (wave >> 1) * 64, wn = (wave & 1) * 64;

    floatx4 acc[4][4];
    #pragma unroll
    for (int i = 0; i < 4; i++)
        #pragma unroll
        for (int j = 0; j < 4; j++) acc[i][j] = (floatx4){0.f, 0.f, 0.f, 0.f};

    const short* Ab = xb  + (size_t)m0 * 512;
    const short* Bb = wqT + (size_t)n0 * 512;

    for (int k0 = 0; k0 < 512; k0 += 64) {
        __syncthreads();
        stage128x64(As, Ab + k0, 512, tid);
        stage128x64(Bs, Bb + k0, 512, tid);
        __syncthreads();
        #pragma unroll
        for (int kh = 0; kh < 2; kh++) {
            short8 a[4], b[4];
            #pragma unroll
            for (int i = 0; i < 4; i++) a[i] = frag64(As, wm + i * 16 + l16, kh * 4 + quad);
            #pragma unroll
            for (int i = 0; i < 4; i++) b[i] = frag64(Bs, wn + i * 16 + l16, kh * 4 + quad);
            #pragma unroll
            for (int mi = 0; mi < 4; mi++)
                #pragma unroll
                for (int ni = 0; ni < 4; ni++)
                    acc[mi][ni] = __builtin_amdgcn_mfma_f32_16x16x32_bf16(
                        a[mi], b[ni], acc[mi][ni], 0, 0, 0);
        }
    }

    // epilogue: transpose through LDS, then coalesced row stores
    __syncthreads();
    short* Tt = smem;                          // [128 cols][136]
    const int doRelu = (n0 < 1024);
    #pragma unroll
    for (int mi = 0; mi < 4; mi++)
        #pragma unroll
        for (int ni = 0; ni < 4; ni++)
            #pragma unroll
            for (int r = 0; r < 4; r++) {
                float v = acc[mi][ni][r];
                if (doRelu) v = fmaxf(v, 0.0f) + EPSF;
                int nl = wn + ni * 16 + l16;            // col within 128
                int ml = wm + mi * 16 + quad * 4 + r;   // row within 128
                Tt[nl * 136 + ml] = f2bf(v);
            }
    __syncthreads();

    const int b = m0 >> 10, m_in = m0 & 1023;
    int row = tid >> 1, half = tid & 1;
    int cg = n0 + row;
    int part = cg >> 9, ci = cg & 511;
    short* base = (part == 0) ? qT : (part == 1) ? kT : vT;
    short* dst = base + ((size_t)b * 512 + ci) * 1024 + m_in + half * 64;
    const short* srcl = &Tt[row * 136 + half * 64];
    // BUGFIX(r3->r4): was i<4 (32 shorts) leaving half of every 64-short
    // half-row unwritten (0xAA poison -> ~28% output error). 8 int4 = 64.
    #pragma unroll
    for (int i = 0; i < 8; i++)
        *(int4*)&dst[i * 8] = *(const int4*)&srcl[i * 8];
}

// ---------------------------------------------------------------------------
// Diffusion GEMM: qd[b][n][c] = sum_m Ad[n][m] * q[b][m][c]  (BT = qT)
// z = b*2 + part(0=q,1=k).  Output bf16 [n][512] rows.
// ---------------------------------------------------------------------------
__global__ __launch_bounds__(256)
void gemm_diff(const short* __restrict__ Ad, const short* __restrict__ qT,
               const short* __restrict__ kT, short* __restrict__ qd,
               short* __restrict__ kd) {
    __shared__ short smem[16384];
    short* As = smem;
    short* Bs = smem + 8192;

    const int tid = threadIdx.x;
    const int z = blockIdx.z, b = z >> 1, part = z & 1;
    const short* BTb = (part ? kT : qT) + (size_t)b * 512 * 1024;
    short* outb = (part ? kd : qd) + (size_t)b * 1024 * 512;

    const int r0 = blockIdx.y * 128;   // n rows
    const int c0 = blockIdx.x * 128;   // c cols
    const int wave = tid >> 6, lane = tid & 63;
    const int quad = lane >> 4, l16 = lane & 15;
    const int wm = (wave >> 1) * 64, wn = (wave & 1) * 64;

    floatx4 acc[4][4];
    #pragma unroll
    for (int i = 0; i < 4; i++)
        #pragma unroll
        for (int j = 0; j < 4; j++) acc[i][j] = (floatx4){0.f, 0.f, 0.f, 0.f};

    const short* Ab = Ad  + (size_t)r0 * 1024;
    const short* Bb = BTb + (size_t)c0 * 1024;

    for (int k0 = 0; k0 < 1024; k0 += 64) {
        __syncthreads();
        stage128x64(As, Ab + k0, 1024, tid);
        stage128x64(Bs, Bb + k0, 1024, tid);
        __syncthreads();
        #pragma unroll
        for (int kh = 0; kh < 2; kh++) {
            short8 a[4], b2[4];
            #pragma unroll
            for (int i = 0; i < 4; i++) a[i]  = frag64(As, wm + i * 16 + l16, kh * 4 + quad);
            #pragma unroll
            for (int i = 0; i < 4; i++) b2[i] = frag64(Bs, wn + i * 16 + l16, kh * 4 + quad);
            #pragma unroll
            for (int mi = 0; mi < 4; mi++)
                #pragma unroll
                for (int ni = 0; ni < 4; ni++)
                    acc[mi][ni] = __builtin_amdgcn_mfma_f32_16x16x32_bf16(
                        a[mi], b2[ni], acc[mi][ni], 0, 0, 0);
        }
    }

    #pragma unroll
    for (int mi = 0; mi < 4; mi++)
        #pragma unroll
        for (int r = 0; r < 4; r++) {
            int n = r0 + wm + mi * 16 + quad * 4 + r;
            #pragma unroll
            for (int ni = 0; ni < 4; ni++) {
                int c = c0 + wn + ni * 16 + l16;
                outb[(size_t)n * 512 + c] = f2bf(acc[mi][ni][r]);
            }
        }
}

// ---------------------------------------------------------------------------
// Masked linear attention via MFMA bf16 (round-2 verified structure,
// bf16 inputs, vT pre-transposed, hi/lo split output).
// ---------------------------------------------------------------------------
#define LDQ 72
#define LDM 68

__global__ __launch_bounds__(256)
void attn_mfma(const short* __restrict__ qd, const short* __restrict__ kd,
               const short* __restrict__ vTg, const float* __restrict__ mask,
               short* __restrict__ ahi, short* __restrict__ alo) {
    __shared__ short qs[64 * LDQ];
    __shared__ short ks[64 * LDQ];
    __shared__ short vt[64 * LDQ];
    __shared__ short ss[64 * LDQ];
    __shared__ float ms[64 * LDM];

    const int tid = threadIdx.x;
    const int bh = blockIdx.y;
    const int b = bh >> 3, h = bh & 7;
    const int n0 = blockIdx.x * 64;

    const int wave = tid >> 6, lane = tid & 63;
    const int quad = lane >> 4, l16 = lane & 15;

    const short* Qb = qd + ((size_t)b * Nn + n0) * Cc + h * Dd;
    const short* Kb = kd + (size_t)b * Nn * Cc + h * Dd;
    const short* Vb = vTg + ((size_t)b * Cc + h * Dd) * Nn;
    const float* Mb = mask + (size_t)n0 * Nn;

    // stage Q once (64 x 64 bf16)
    #pragma unroll
    for (int i = 0; i < 2; i++) {
        int idx = i * 256 + tid;
        int r = idx >> 3, c = idx & 7;
        *(int4*)&qs[r * LDQ + c * 8] = *(const int4*)&Qb[(size_t)r * Cc + c * 8];
    }

    float dreg[4] = {0.f, 0.f, 0.f, 0.f};
    floatx4 nacc[4];
    #pragma unroll
    for (int i = 0; i < 4; i++) nacc[i] = (floatx4){0.f, 0.f, 0.f, 0.f};

    for (int m0 = 0; m0 < Nn; m0 += 64) {
        __syncthreads();
        #pragma unroll
        for (int i = 0; i < 2; i++) {
            int idx = i * 256 + tid;
            int r = idx >> 3, c = idx & 7;
            *(int4*)&ks[r * LDQ + c * 8] = *(const int4*)&Kb[(size_t)(m0 + r) * Cc + c * 8];
            *(int4*)&vt[r * LDQ + c * 8] = *(const int4*)&Vb[(size_t)r * Nn + m0 + c * 8];
        }
        #pragma unroll
        for (int i = 0; i < 4; i++) {
            int idx = i * 256 + tid;
            int r = idx >> 4, c4 = (idx & 15) * 4;
            *(float4*)&ms[r * LDM + c4] = *(const float4*)&Mb[(size_t)r * Nn + m0 + c4];
        }
        __syncthreads();

        // phase A: S = (Q K^T) * mask (fp32) -> ss (bf16), denom acc
        const short8 a0 = *(const short8*)&qs[(wave * 16 + l16) * LDQ + 0  + quad * 8];
        const short8 a1 = *(const short8*)&qs[(wave * 16 + l16) * LDQ + 32 + quad * 8];
        #pragma unroll
        for (int mt = 0; mt < 4; mt++) {
            const short8 b0 = *(const short8*)&ks[(mt * 16 + l16) * LDQ + 0  + quad * 8];
            const short8 b1 = *(const short8*)&ks[(mt * 16 + l16) * LDQ + 32 + quad * 8];
            floatx4 s = (floatx4){0.f, 0.f, 0.f, 0.f};
            s = __builtin_amdgcn_mfma_f32_16x16x32_bf16(a0, b0, s, 0, 0, 0);
            s = __builtin_amdgcn_mfma_f32_16x16x32_bf16(a1, b1, s, 0, 0, 0);
            #pragma unroll
            for (int r = 0; r < 4; r++) {
                int rl = wave * 16 + quad * 4 + r;
                float sv = s[r] * ms[rl * LDM + mt * 16 + l16];
                dreg[r] += sv;
                ss[rl * LDQ + mt * 16 + l16] = f2bf(sv);
            }
        }
        __syncthreads();

        // phase B: num += S @ V
        const short8 p0 = *(const short8*)&ss[(wave * 16 + l16) * LDQ + 0  + quad * 8];
        const short8 p1 = *(const short8*)&ss[(wave * 16 + l16) * LDQ + 32 + quad * 8];
        #pragma unroll
        for (int dt = 0; dt < 4; dt++) {
            const short8 v0 = *(const short8*)&vt[(dt * 16 + l16) * LDQ + 0  + quad * 8];
            const short8 v1 = *(const short8*)&vt[(dt * 16 + l16) * LDQ + 32 + quad * 8];
            nacc[dt] = __builtin_amdgcn_mfma_f32_16x16x32_bf16(p0, v0, nacc[dt], 0, 0, 0);
            nacc[dt] = __builtin_amdgcn_mfma_f32_16x16x32_bf16(p1, v1, nacc[dt], 0, 0, 0);
        }
    }

    #pragma unroll
    for (int r = 0; r < 4; r++) {
        #pragma unroll
        for (int off = 1; off < 16; off <<= 1)
            dreg[r] += __shfl_xor(dreg[r], off, 64);
    }

    #pragma unroll
    for (int r = 0; r < 4; r++) {
        int n = n0 + wave * 16 + quad * 4 + r;
        float zr = 1.0f / (dreg[r] + EPSF);
        #pragma unroll
        for (int dt = 0; dt < 4; dt++) {
            float val = nacc[dt][r] * zr;
            short hi = f2bf(val);
            short lo = f2bf(val - bf2f(hi));
            size_t o = ((size_t)b * Nn + n) * Cc + h * Dd + dt * 16 + l16;
            ahi[o] = hi;
            alo[o] = lo;
        }
    }
}

// ---------------------------------------------------------------------------
// Output GEMM (bf16x3 split): out = Ahi@Whi + Ahi@Wlo + Alo@Whi + bias (fp32)
// ---------------------------------------------------------------------------
__global__ __launch_bounds__(256)
void gemm_out(const short* __restrict__ ahi, const short* __restrict__ alo,
              const short* __restrict__ whi, const short* __restrict__ wlo,
              const float* __restrict__ bias, float* __restrict__ out) {
    __shared__ short smem[32768];      // 64 KB
    short* Ah = smem;
    short* Al = smem + 8192;
    short* Bh = smem + 16384;
    short* Bl = smem + 24576;

    const int tid = threadIdx.x;
    const int m0 = blockIdx.y * 128;
    const int n0 = blockIdx.x * 128;
    const int wave = tid >> 6, lane = tid & 63;
    const int quad = lane >> 4, l16 = lane & 15;
    const int wm = (wave >> 1) * 64, wn = (wave & 1) * 64;

    floatx4 acc[4][4];
    #pragma unroll
    for (int i = 0; i < 4; i++)
        #pragma unroll
        for (int j = 0; j < 4; j++) acc[i][j] = (floatx4){0.f, 0.f, 0.f, 0.f};

    const short* Ahb = ahi + (size_t)m0 * 512;
    const short* Alb = alo + (size_t)m0 * 512;
    const short* Bhb = whi + (size_t)n0 * 512;
    const short* Blb = wlo + (size_t)n0 * 512;

    for (int k0 = 0; k0 < 512; k0 += 64) {
        __syncthreads();
        stage128x64(Ah, Ahb + k0, 512, tid);
        stage128x64(Al, Alb + k0, 512, tid);
        stage128x64(Bh, Bhb + k0, 512, tid);
        stage128x64(Bl, Blb + k0, 512, tid);
        __syncthreads();
        #pragma unroll
        for (int kh = 0; kh < 2; kh++) {
            short8 ah[4], al[4], bh[4], bl[4];
            #pragma unroll
            for (int i = 0; i < 4; i++) {
                ah[i] = frag64(Ah, wm + i * 16 + l16, kh * 4 + quad);
                al[i] = frag64(Al, wm + i * 16 + l16, kh * 4 + quad);
                bh[i] = frag64(Bh, wn + i * 16 + l16, kh * 4 + quad);
                bl[i] = frag64(Bl, wn + i * 16 + l16, kh * 4 + quad);
            }
            #pragma unroll
            for (int mi = 0; mi < 4; mi++)
                #pragma unroll
                for (int ni = 0; ni < 4; ni++) {
                    acc[mi][ni] = __builtin_amdgcn_mfma_f32_16x16x32_bf16(
                        ah[mi], bh[ni], acc[mi][ni], 0, 0, 0);
                    acc[mi][ni] = __builtin_amdgcn_mfma_f32_16x16x32_bf16(
                        ah[mi], bl[ni], acc[mi][ni], 0, 0, 0);
                    acc[mi][ni] = __builtin_amdgcn_mfma_f32_16x16x32_bf16(
                        al[mi], bh[ni], acc[mi][ni], 0, 0, 0);
                }
        }
    }

    #pragma unroll
    for (int mi = 0; mi < 4; mi++)
        #pragma unroll
        for (int r = 0; r < 4; r++) {
            int m = m0 + wm + mi * 16 + quad * 4 + r;
            #pragma unroll
            for (int ni = 0; ni < 4; ni++) {
                int n = n0 + wn + ni * 16 + l16;
                out[(size_t)m * 512 + n] = acc[mi][ni][r] + bias[n];
            }
        }
}

// ---------------------------------------------------------------------------
extern "C" void kernel_launch(void* const* d_in, const int* in_sizes, int n_in,
                              void* d_out, int out_size, void* d_ws, size_t ws_size,
                              hipStream_t stream) {
    const float* x     = (const float*)d_in[0];
    const float* mask  = (const float*)d_in[1];
    const float* w_qkv = (const float*)d_in[2];
    const float* w_out = (const float*)d_in[3];
    const float* b_out = (const float*)d_in[4];
    float* out = (float*)d_out;

    char* p = (char*)d_ws;
    short* xb  = (short*)p; p += 8388608;      // [8192][512]
    short* wqT = (short*)p; p += 1572864;      // [1536][512]
    short* Ad  = (short*)p; p += 2097152;      // [1024][1024]
    short* whi = (short*)p; p += 524288;       // [512][512]
    short* wlo = (short*)p; p += 524288;
    short* qT  = (short*)p; p += 8388608;      // [b][512][1024]
    short* kT  = (short*)p; p += 8388608;
    short* vT  = (short*)p; p += 8388608;
    short* qd  = (short*)p; p += 8388608;      // [b][1024][512]
    short* kd  = (short*)p; p += 8388608;
    short* ahi = (short*)p; p += 8388608;      // [8192][512]
    short* alo = (short*)p; p += 8388608;

    dim3 blk(256);

    prep_x    <<<2048, blk, 0, stream>>>(x, xb);
    prep_adiff<<<dim3(16, 16), blk, 0, stream>>>(mask, Ad);
    prep_wq   <<<dim3(24, 8),  blk, 0, stream>>>(w_qkv, wqT);
    prep_wo   <<<dim3(8, 8),   blk, 0, stream>>>(w_out, whi, wlo);

    gemm_qkv  <<<dim3(12, 64), blk, 0, stream>>>(xb, wqT, qT, kT, vT);
    gemm_diff <<<dim3(4, 8, 16), blk, 0, stream>>>(Ad, qT, kT, qd, kd);
    attn_mfma <<<dim3(16, 64), blk, 0, stream>>>(qd, kd, vT, mask, ahi, alo);
    gemm_out  <<<dim3(4, 64),  blk, 0, stream>>>(ahi, alo, whi, wlo, b_out, out);
}

// Round 5
// 203.049 us; speedup vs baseline: 7.9887x; 1.0984x over previous
//
#include <hip/hip_runtime.h>
#include <cstddef>

// Problem constants
#define Bsz 8
#define Nn  1024
#define Cc  512
#define Hh  8
#define Dd  64
#define EPSF 1e-6f

typedef __attribute__((ext_vector_type(8))) short short8;   // 8 bf16 (4 VGPRs)
typedef __attribute__((ext_vector_type(4))) float floatx4;  // MFMA accumulator

// round-to-nearest-even fp32 -> bf16 (bit pattern in a short)
static __device__ __forceinline__ short f2bf(float f) {
    union { float f; unsigned u; } v; v.f = f;
    unsigned r = (v.u + 0x7FFFu + ((v.u >> 16) & 1u)) >> 16;
    return (short)r;
}
static __device__ __forceinline__ float bf2f(short s) {
    union { unsigned u; float f; } v; v.u = ((unsigned)(unsigned short)s) << 16;
    return v.f;
}

// ---------------------------------------------------------------------------
// XOR-swizzled LDS tile, linear 16B slots (lane-linear => global_load_lds ok).
// Slot s holds row r=s/8, global chunk (s%8)^(r%8).  Element (r,c) is at
// short offset (r*8 + ((c>>3)^(r&7)))*8 + (c&7).
// ---------------------------------------------------------------------------
#define GLOAD_LDS16(gp, lp)                                              \
    __builtin_amdgcn_global_load_lds(                                    \
        (const __attribute__((address_space(1))) void*)(gp),             \
        (__attribute__((address_space(3))) void*)(lp), 16, 0, 0)

// 128 rows x 64 cols (1024 slots, 4/thread)
static __device__ __forceinline__
void stage_async128(short* __restrict__ lds, const short* __restrict__ src,
                    int ldsrc, int tid) {
    #pragma unroll
    for (int i = 0; i < 4; i++) {
        int s = i * 256 + tid;
        int r = s >> 3, cs = s & 7;
        int gc = cs ^ (r & 7);
        GLOAD_LDS16(&src[(size_t)r * ldsrc + gc * 8], &lds[s * 8]);
    }
}
// 64 rows x 64 cols (512 slots, 2/thread)
static __device__ __forceinline__
void stage_async64(short* __restrict__ lds, const short* __restrict__ src,
                   int ldsrc, int tid) {
    #pragma unroll
    for (int i = 0; i < 2; i++) {
        int s = i * 256 + tid;
        int r = s >> 3, cs = s & 7;
        int gc = cs ^ (r & 7);
        GLOAD_LDS16(&src[(size_t)r * ldsrc + gc * 8], &lds[s * 8]);
    }
}
static __device__ __forceinline__
short8 frag64(const short* __restrict__ lds, int r, int lc) {
    return *(const short8*)&lds[(r * 8 + (lc ^ (r & 7))) * 8];
}
static __device__ __forceinline__ int swz(int r, int c) {   // short offset
    return (r * 8 + (((c) >> 3) ^ (r & 7))) * 8 + ((c) & 7);
}

// ---------------------------------------------------------------------------
// Merged prep: blocks [0,2048) cvt x->bf16; [2048,2304) diffusion operator;
// [2304,2496) w_qkv^T; [2496,2560) w_out^T hi/lo split.
// ---------------------------------------------------------------------------
__global__ __launch_bounds__(256)
void prep_all(const float* __restrict__ x, const float* __restrict__ mask,
              const float* __restrict__ wq, const float* __restrict__ wo,
              short* __restrict__ xb, short* __restrict__ Ad,
              short* __restrict__ wqT, short* __restrict__ whi,
              short* __restrict__ wlo) {
    __shared__ float t[64][65];
    const int tid = threadIdx.x;
    const int bid = blockIdx.x;

    if (bid < 2048) {                       // x -> bf16, 8 elems/thread
        int idx = bid * 256 + tid;
        const float* s = &x[(size_t)idx * 8];
        union { short h[8]; int4 v; } u;
        #pragma unroll
        for (int j = 0; j < 8; j++) u.h[j] = f2bf(s[j]);
        *(int4*)&xb[(size_t)idx * 8] = u.v;
        return;
    }
    if (bid < 2304) {                       // Ad[n][m] = bf16(I + 0.1*mask^T)
        int idx = bid - 2048;
        const int n0 = (idx & 15) * 64, m0 = (idx >> 4) * 64;
        #pragma unroll
        for (int i = 0; i < 4; i++) {
            int k = i * 256 + tid;
            int r = k >> 4, c4 = (k & 15) * 4;
            *(float4*)&t[r][c4] = *(const float4*)&mask[(size_t)(m0 + r) * Nn + n0 + c4];
        }
        __syncthreads();
        #pragma unroll
        for (int i = 0; i < 4; i++) {
            int k = i * 256 + tid;
            int rr = k >> 4, c4 = (k & 15) * 4;
            union { short h[4]; int2 v; } u;
            #pragma unroll
            for (int j = 0; j < 4; j++) {
                int mm = c4 + j;
                float v = 0.1f * t[mm][rr] + ((n0 + rr) == (m0 + mm) ? 1.0f : 0.0f);
                u.h[j] = f2bf(v);
            }
            *(int2*)&Ad[(size_t)(n0 + rr) * Nn + m0 + c4] = u.v;
        }
        return;
    }
    if (bid < 2496) {                       // wqT[n][k] = bf16(wq[k][n])
        int idx = bid - 2304;
        const int n0 = (idx % 24) * 64, k0 = (idx / 24) * 64;
        #pragma unroll
        for (int i = 0; i < 4; i++) {
            int k = i * 256 + tid;
            int r = k >> 4, c4 = (k & 15) * 4;
            *(float4*)&t[r][c4] = *(const float4*)&wq[(size_t)(k0 + r) * 1536 + n0 + c4];
        }
        __syncthreads();
        #pragma unroll
        for (int i = 0; i < 4; i++) {
            int k = i * 256 + tid;
            int rr = k >> 4, c4 = (k & 15) * 4;
            union { short h[4]; int2 v; } u;
            #pragma unroll
            for (int j = 0; j < 4; j++) u.h[j] = f2bf(t[c4 + j][rr]);
            *(int2*)&wqT[(size_t)(n0 + rr) * 512 + k0 + c4] = u.v;
        }
        return;
    }
    {                                        // woT hi/lo
        int idx = bid - 2496;
        const int n0 = (idx & 7) * 64, k0 = (idx >> 3) * 64;
        #pragma unroll
        for (int i = 0; i < 4; i++) {
            int k = i * 256 + tid;
            int r = k >> 4, c4 = (k & 15) * 4;
            *(float4*)&t[r][c4] = *(const float4*)&wo[(size_t)(k0 + r) * 512 + n0 + c4];
        }
        __syncthreads();
        #pragma unroll
        for (int i = 0; i < 4; i++) {
            int k = i * 256 + tid;
            int rr = k >> 4, c4 = (k & 15) * 4;
            union { short h[4]; int2 v; } uh, ul;
            #pragma unroll
            for (int j = 0; j < 4; j++) {
                float v = t[c4 + j][rr];
                short hi = f2bf(v);
                uh.h[j] = hi;
                ul.h[j] = f2bf(v - bf2f(hi));
            }
            *(int2*)&whi[(size_t)(n0 + rr) * 512 + k0 + c4] = uh.v;
            *(int2*)&wlo[(size_t)(n0 + rr) * 512 + k0 + c4] = ul.v;
        }
    }
}

// ---------------------------------------------------------------------------
// GEMM1: qkv = xb[8192][512] @ wqT^T, relu+eps on cols<1024.
// Epilogue: LDS transpose, writes qT/kT/vT[b][c][m] bf16 (B-operand layout).
// ---------------------------------------------------------------------------
__global__ __launch_bounds__(256)
void gemm_qkv(const short* __restrict__ xb, const short* __restrict__ wqT,
              short* __restrict__ qT, short* __restrict__ kT,
              short* __restrict__ vT) {
    __shared__ short smem[17408];             // 34816 B
    short* As = smem;
    short* Bs = smem + 8192;

    const int tid = threadIdx.x;
    const int m0 = blockIdx.y * 128;
    const int n0 = blockIdx.x * 128;
    const int wave = tid >> 6, lane = tid & 63;
    const int quad = lane >> 4, l16 = lane & 15;
    const int wm = (wave >> 1) * 64, wn = (wave & 1) * 64;

    floatx4 acc[4][4];
    #pragma unroll
    for (int i = 0; i < 4; i++)
        #pragma unroll
        for (int j = 0; j < 4; j++) acc[i][j] = (floatx4){0.f, 0.f, 0.f, 0.f};

    const short* Ab = xb  + (size_t)m0 * 512;
    const short* Bb = wqT + (size_t)n0 * 512;

    for (int k0 = 0; k0 < 512; k0 += 64) {
        __syncthreads();
        stage_async128(As, Ab + k0, 512, tid);
        stage_async128(Bs, Bb + k0, 512, tid);
        __syncthreads();
        #pragma unroll
        for (int kh = 0; kh < 2; kh++) {
            short8 a[4], b[4];
            #pragma unroll
            for (int i = 0; i < 4; i++) a[i] = frag64(As, wm + i * 16 + l16, kh * 4 + quad);
            #pragma unroll
            for (int i = 0; i < 4; i++) b[i] = frag64(Bs, wn + i * 16 + l16, kh * 4 + quad);
            #pragma unroll
            for (int mi = 0; mi < 4; mi++)
                #pragma unroll
                for (int ni = 0; ni < 4; ni++)
                    acc[mi][ni] = __builtin_amdgcn_mfma_f32_16x16x32_bf16(
                        a[mi], b[ni], acc[mi][ni], 0, 0, 0);
        }
    }

    __syncthreads();
    short* Tt = smem;                          // [128 cols][136]
    const int doRelu = (n0 < 1024);
    #pragma unroll
    for (int mi = 0; mi < 4; mi++)
        #pragma unroll
        for (int ni = 0; ni < 4; ni++)
            #pragma unroll
            for (int r = 0; r < 4; r++) {
                float v = acc[mi][ni][r];
                if (doRelu) v = fmaxf(v, 0.0f) + EPSF;
                int nl = wn + ni * 16 + l16;
                int ml = wm + mi * 16 + quad * 4 + r;
                Tt[nl * 136 + ml] = f2bf(v);
            }
    __syncthreads();

    const int b = m0 >> 10, m_in = m0 & 1023;
    int row = tid >> 1, half = tid & 1;
    int cg = n0 + row;
    int part = cg >> 9, ci = cg & 511;
    short* base = (part == 0) ? qT : (part == 1) ? kT : vT;
    short* dst = base + ((size_t)b * 512 + ci) * 1024 + m_in + half * 64;
    const short* srcl = &Tt[row * 136 + half * 64];
    #pragma unroll
    for (int i = 0; i < 8; i++)     // 8 x int4 = full 64-short half-row
        *(int4*)&dst[i * 8] = *(const int4*)&srcl[i * 8];
}

// ---------------------------------------------------------------------------
// Diffusion GEMM: qd[b][n][c] = sum_m Ad[n][m] * q[b][m][c]  (BT = qT)
// ---------------------------------------------------------------------------
__global__ __launch_bounds__(256)
void gemm_diff(const short* __restrict__ Ad, const short* __restrict__ qT,
               const short* __restrict__ kT, short* __restrict__ qd,
               short* __restrict__ kd) {
    __shared__ short smem[16384];
    short* As = smem;
    short* Bs = smem + 8192;

    const int tid = threadIdx.x;
    const int z = blockIdx.z, b = z >> 1, part = z & 1;
    const short* BTb = (part ? kT : qT) + (size_t)b * 512 * 1024;
    short* outb = (part ? kd : qd) + (size_t)b * 1024 * 512;

    const int r0 = blockIdx.y * 128;
    const int c0 = blockIdx.x * 128;
    const int wave = tid >> 6, lane = tid & 63;
    const int quad = lane >> 4, l16 = lane & 15;
    const int wm = (wave >> 1) * 64, wn = (wave & 1) * 64;

    floatx4 acc[4][4];
    #pragma unroll
    for (int i = 0; i < 4; i++)
        #pragma unroll
        for (int j = 0; j < 4; j++) acc[i][j] = (floatx4){0.f, 0.f, 0.f, 0.f};

    const short* Ab = Ad  + (size_t)r0 * 1024;
    const short* Bb = BTb + (size_t)c0 * 1024;

    for (int k0 = 0; k0 < 1024; k0 += 64) {
        __syncthreads();
        stage_async128(As, Ab + k0, 1024, tid);
        stage_async128(Bs, Bb + k0, 1024, tid);
        __syncthreads();
        #pragma unroll
        for (int kh = 0; kh < 2; kh++) {
            short8 a[4], b2[4];
            #pragma unroll
            for (int i = 0; i < 4; i++) a[i]  = frag64(As, wm + i * 16 + l16, kh * 4 + quad);
            #pragma unroll
            for (int i = 0; i < 4; i++) b2[i] = frag64(Bs, wn + i * 16 + l16, kh * 4 + quad);
            #pragma unroll
            for (int mi = 0; mi < 4; mi++)
                #pragma unroll
                for (int ni = 0; ni < 4; ni++)
                    acc[mi][ni] = __builtin_amdgcn_mfma_f32_16x16x32_bf16(
                        a[mi], b2[ni], acc[mi][ni], 0, 0, 0);
        }
    }

    #pragma unroll
    for (int mi = 0; mi < 4; mi++)
        #pragma unroll
        for (int r = 0; r < 4; r++) {
            int n = r0 + wm + mi * 16 + quad * 4 + r;
            #pragma unroll
            for (int ni = 0; ni < 4; ni++) {
                int c = c0 + wn + ni * 16 + l16;
                outb[(size_t)n * 512 + c] = f2bf(acc[mi][ni][r]);
            }
        }
}

// ---------------------------------------------------------------------------
// Masked linear attention (MFMA bf16, flash-style).
// Swizzled 64x64 LDS tiles, async staging, mask read direct from global
// (fp32, L2/L3-resident), no phase A->B barrier (waves own their ss rows).
// LDS 32 KB -> 4 blocks/CU.
// ---------------------------------------------------------------------------
__global__ __launch_bounds__(256)
void attn_mfma(const short* __restrict__ qd, const short* __restrict__ kd,
               const short* __restrict__ vTg, const float* __restrict__ mask,
               short* __restrict__ ahi, short* __restrict__ alo) {
    __shared__ short qs[4096];
    __shared__ short ks[4096];
    __shared__ short vt[4096];
    __shared__ short ss[4096];

    const int tid = threadIdx.x;
    const int bh = blockIdx.y;
    const int b = bh >> 3, h = bh & 7;
    const int n0 = blockIdx.x * 64;

    const int wave = tid >> 6, lane = tid & 63;
    const int quad = lane >> 4, l16 = lane & 15;

    const short* Qb = qd + ((size_t)b * Nn + n0) * Cc + h * Dd;        // stride Cc
    const short* Kb = kd + (size_t)b * Nn * Cc + h * Dd;               // stride Cc
    const short* Vb = vTg + ((size_t)b * Cc + h * Dd) * Nn;            // stride Nn
    const float* Mb = mask + (size_t)n0 * Nn;

    stage_async64(qs, Qb, Cc, tid);
    __syncthreads();                          // qs resident (vmcnt drained)
    const short8 a0 = frag64(qs, wave * 16 + l16, quad);
    const short8 a1 = frag64(qs, wave * 16 + l16, 4 + quad);

    float dreg[4] = {0.f, 0.f, 0.f, 0.f};
    floatx4 nacc[4];
    #pragma unroll
    for (int i = 0; i < 4; i++) nacc[i] = (floatx4){0.f, 0.f, 0.f, 0.f};

    for (int m0 = 0; m0 < Nn; m0 += 64) {
        __syncthreads();                      // prior chunk's ks/vt readers done
        stage_async64(ks, Kb + (size_t)m0 * Cc, Cc, tid);
        stage_async64(vt, Vb + m0, Nn, tid);
        __syncthreads();                      // staged data visible

        // phase A: S = (Q K^T) * mask (fp32) -> ss (bf16), denom acc
        #pragma unroll
        for (int mt = 0; mt < 4; mt++) {
            const short8 b0 = frag64(ks, mt * 16 + l16, quad);
            const short8 b1 = frag64(ks, mt * 16 + l16, 4 + quad);
            floatx4 s = (floatx4){0.f, 0.f, 0.f, 0.f};
            s = __builtin_amdgcn_mfma_f32_16x16x32_bf16(a0, b0, s, 0, 0, 0);
            s = __builtin_amdgcn_mfma_f32_16x16x32_bf16(a1, b1, s, 0, 0, 0);
            #pragma unroll
            for (int r = 0; r < 4; r++) {
                int rl = wave * 16 + quad * 4 + r;
                float mv = Mb[(size_t)rl * Nn + m0 + mt * 16 + l16];
                float sv = s[r] * mv;
                dreg[r] += sv;
                ss[swz(rl, mt * 16 + l16)] = f2bf(sv);
            }
        }
        // no barrier: this wave reads exactly the ss rows it wrote
        // (within-wave lgkmcnt ordering suffices)

        // phase B: num += S @ V
        const short8 p0 = frag64(ss, wave * 16 + l16, quad);
        const short8 p1 = frag64(ss, wave * 16 + l16, 4 + quad);
        #pragma unroll
        for (int dt = 0; dt < 4; dt++) {
            const short8 v0 = frag64(vt, dt * 16 + l16, quad);
            const short8 v1 = frag64(vt, dt * 16 + l16, 4 + quad);
            nacc[dt] = __builtin_amdgcn_mfma_f32_16x16x32_bf16(p0, v0, nacc[dt], 0, 0, 0);
            nacc[dt] = __builtin_amdgcn_mfma_f32_16x16x32_bf16(p1, v1, nacc[dt], 0, 0, 0);
        }
    }

    #pragma unroll
    for (int r = 0; r < 4; r++) {
        #pragma unroll
        for (int off = 1; off < 16; off <<= 1)
            dreg[r] += __shfl_xor(dreg[r], off, 64);
    }

    #pragma unroll
    for (int r = 0; r < 4; r++) {
        int n = n0 + wave * 16 + quad * 4 + r;
        float zr = 1.0f / (dreg[r] + EPSF);
        #pragma unroll
        for (int dt = 0; dt < 4; dt++) {
            float val = nacc[dt][r] * zr;
            short hi = f2bf(val);
            short lo = f2bf(val - bf2f(hi));
            size_t o = ((size_t)b * Nn + n) * Cc + h * Dd + dt * 16 + l16;
            ahi[o] = hi;
            alo[o] = lo;
        }
    }
}

// ---------------------------------------------------------------------------
// Output GEMM (bf16x3 split): out = Ahi@Whi + Ahi@Wlo + Alo@Whi + bias (fp32)
// ---------------------------------------------------------------------------
__global__ __launch_bounds__(256)
void gemm_out(const short* __restrict__ ahi, const short* __restrict__ alo,
              const short* __restrict__ whi, const short* __restrict__ wlo,
              const float* __restrict__ bias, float* __restrict__ out) {
    __shared__ short smem[32768];      // 64 KB
    short* Ah = smem;
    short* Al = smem + 8192;
    short* Bh = smem + 16384;
    short* Bl = smem + 24576;

    const int tid = threadIdx.x;
    const int m0 = blockIdx.y * 128;
    const int n0 = blockIdx.x * 128;
    const int wave = tid >> 6, lane = tid & 63;
    const int quad = lane >> 4, l16 = lane & 15;
    const int wm = (wave >> 1) * 64, wn = (wave & 1) * 64;

    floatx4 acc[4][4];
    #pragma unroll
    for (int i = 0; i < 4; i++)
        #pragma unroll
        for (int j = 0; j < 4; j++) acc[i][j] = (floatx4){0.f, 0.f, 0.f, 0.f};

    const short* Ahb = ahi + (size_t)m0 * 512;
    const short* Alb = alo + (size_t)m0 * 512;
    const short* Bhb = whi + (size_t)n0 * 512;
    const short* Blb = wlo + (size_t)n0 * 512;

    for (int k0 = 0; k0 < 512; k0 += 64) {
        __syncthreads();
        stage_async128(Ah, Ahb + k0, 512, tid);
        stage_async128(Al, Alb + k0, 512, tid);
        stage_async128(Bh, Bhb + k0, 512, tid);
        stage_async128(Bl, Blb + k0, 512, tid);
        __syncthreads();
        #pragma unroll
        for (int kh = 0; kh < 2; kh++) {
            short8 ah[4], al[4], bh[4], bl[4];
            #pragma unroll
            for (int i = 0; i < 4; i++) {
                ah[i] = frag64(Ah, wm + i * 16 + l16, kh * 4 + quad);
                al[i] = frag64(Al, wm + i * 16 + l16, kh * 4 + quad);
                bh[i] = frag64(Bh, wn + i * 16 + l16, kh * 4 + quad);
                bl[i] = frag64(Bl, wn + i * 16 + l16, kh * 4 + quad);
            }
            #pragma unroll
            for (int mi = 0; mi < 4; mi++)
                #pragma unroll
                for (int ni = 0; ni < 4; ni++) {
                    acc[mi][ni] = __builtin_amdgcn_mfma_f32_16x16x32_bf16(
                        ah[mi], bh[ni], acc[mi][ni], 0, 0, 0);
                    acc[mi][ni] = __builtin_amdgcn_mfma_f32_16x16x32_bf16(
                        ah[mi], bl[ni], acc[mi][ni], 0, 0, 0);
                    acc[mi][ni] = __builtin_amdgcn_mfma_f32_16x16x32_bf16(
                        al[mi], bh[ni], acc[mi][ni], 0, 0, 0);
                }
        }
    }

    #pragma unroll
    for (int mi = 0; mi < 4; mi++)
        #pragma unroll
        for (int r = 0; r < 4; r++) {
            int m = m0 + wm + mi * 16 + quad * 4 + r;
            #pragma unroll
            for (int ni = 0; ni < 4; ni++) {
                int n = n0 + wn + ni * 16 + l16;
                out[(size_t)m * 512 + n] = acc[mi][ni][r] + bias[n];
            }
        }
}

// ---------------------------------------------------------------------------
extern "C" void kernel_launch(void* const* d_in, const int* in_sizes, int n_in,
                              void* d_out, int out_size, void* d_ws, size_t ws_size,
                              hipStream_t stream) {
    const float* x     = (const float*)d_in[0];
    const float* mask  = (const float*)d_in[1];
    const float* w_qkv = (const float*)d_in[2];
    const float* w_out = (const float*)d_in[3];
    const float* b_out = (const float*)d_in[4];
    float* out = (float*)d_out;

    char* p = (char*)d_ws;
    short* xb  = (short*)p; p += 8388608;      // [8192][512]
    short* wqT = (short*)p; p += 1572864;      // [1536][512]
    short* Ad  = (short*)p; p += 2097152;      // [1024][1024]
    short* whi = (short*)p; p += 524288;       // [512][512]
    short* wlo = (short*)p; p += 524288;
    short* qT  = (short*)p; p += 8388608;      // [b][512][1024]
    short* kT  = (short*)p; p += 8388608;
    short* vT  = (short*)p; p += 8388608;
    short* qd  = (short*)p; p += 8388608;      // [b][1024][512]
    short* kd  = (short*)p; p += 8388608;
    short* ahi = (short*)p; p += 8388608;      // [8192][512]
    short* alo = (short*)p; p += 8388608;

    dim3 blk(256);

    prep_all  <<<2560, blk, 0, stream>>>(x, mask, w_qkv, w_out,
                                         xb, Ad, wqT, whi, wlo);
    gemm_qkv  <<<dim3(12, 64), blk, 0, stream>>>(xb, wqT, qT, kT, vT);
    gemm_diff <<<dim3(4, 8, 16), blk, 0, stream>>>(Ad, qT, kT, qd, kd);
    attn_mfma <<<dim3(16, 64), blk, 0, stream>>>(qd, kd, vT, mask, ahi, alo);
    gemm_out  <<<dim3(4, 64),  blk, 0, stream>>>(ahi, alo, whi, wlo, b_out, out);
}

// Round 6
// 188.158 us; speedup vs baseline: 8.6209x; 1.0791x over previous
//
#include <hip/hip_runtime.h>
#include <cstddef>

// Problem constants
#define Bsz 8
#define Nn  1024
#define Cc  512
#define Hh  8
#define Dd  64
#define EPSF 1e-6f

typedef __attribute__((ext_vector_type(8))) short short8;   // 8 bf16 (4 VGPRs)
typedef __attribute__((ext_vector_type(4))) float floatx4;  // MFMA accumulator

// round-to-nearest-even fp32 -> bf16 (bit pattern in a short)
static __device__ __forceinline__ short f2bf(float f) {
    union { float f; unsigned u; } v; v.f = f;
    unsigned r = (v.u + 0x7FFFu + ((v.u >> 16) & 1u)) >> 16;
    return (short)r;
}
static __device__ __forceinline__ float bf2f(short s) {
    union { unsigned u; float f; } v; v.u = ((unsigned)(unsigned short)s) << 16;
    return v.f;
}

// ---------------------------------------------------------------------------
// XOR-swizzled LDS tiles, linear 16B slots (lane-linear => global_load_lds ok).
// Tile = ROWS x (CHUNKS*8) bf16.  Slot s holds row r=s/CHUNKS, global chunk
// (s%CHUNKS)^(r&7).  Fragment read for row r, logical chunk lc is slot
// r*CHUNKS + (lc^(r&7)) -> bank-balanced ds_read_b128.
// ---------------------------------------------------------------------------
#define GLOAD_LDS16(gp, lp)                                              \
    __builtin_amdgcn_global_load_lds(                                    \
        (const __attribute__((address_space(1))) void*)(gp),             \
        (__attribute__((address_space(3))) void*)(lp), 16, 0, 0)

static __device__ __forceinline__
void stage_tile(short* __restrict__ lds, const short* __restrict__ src,
                int ldsrc, int tid, int CHUNKS, int SLOTS) {
    #pragma unroll
    for (int s = tid; s < SLOTS; s += 256) {
        int r = s / CHUNKS, cs = s % CHUNKS;
        int gc = cs ^ (r & 7);
        GLOAD_LDS16(&src[(size_t)r * ldsrc + gc * 8], &lds[s * 8]);
    }
}
static __device__ __forceinline__
short8 fragT(const short* __restrict__ lds, int CHUNKS, int r, int lc) {
    return *(const short8*)&lds[(r * CHUNKS + (lc ^ (r & 7))) * 8];
}
static __device__ __forceinline__ int swz8(int r, int c) {   // CHUNKS=8 offset
    return (r * 8 + (((c) >> 3) ^ (r & 7))) * 8 + ((c) & 7);
}

// ---------------------------------------------------------------------------
// Merged prep: blocks [0,2048) cvt x->bf16; [2048,2304) diffusion operator;
// [2304,2496) w_qkv^T; [2496,2560) w_out^T hi/lo split.
// ---------------------------------------------------------------------------
__global__ __launch_bounds__(256)
void prep_all(const float* __restrict__ x, const float* __restrict__ mask,
              const float* __restrict__ wq, const float* __restrict__ wo,
              short* __restrict__ xb, short* __restrict__ Ad,
              short* __restrict__ wqT, short* __restrict__ whi,
              short* __restrict__ wlo) {
    __shared__ float t[64][65];
    const int tid = threadIdx.x;
    const int bid = blockIdx.x;

    if (bid < 2048) {                       // x -> bf16, 8 elems/thread
        int idx = bid * 256 + tid;
        const float* s = &x[(size_t)idx * 8];
        union { short h[8]; int4 v; } u;
        #pragma unroll
        for (int j = 0; j < 8; j++) u.h[j] = f2bf(s[j]);
        *(int4*)&xb[(size_t)idx * 8] = u.v;
        return;
    }
    if (bid < 2304) {                       // Ad[n][m] = bf16(I + 0.1*mask^T)
        int idx = bid - 2048;
        const int n0 = (idx & 15) * 64, m0 = (idx >> 4) * 64;
        #pragma unroll
        for (int i = 0; i < 4; i++) {
            int k = i * 256 + tid;
            int r = k >> 4, c4 = (k & 15) * 4;
            *(float4*)&t[r][c4] = *(const float4*)&mask[(size_t)(m0 + r) * Nn + n0 + c4];
        }
        __syncthreads();
        #pragma unroll
        for (int i = 0; i < 4; i++) {
            int k = i * 256 + tid;
            int rr = k >> 4, c4 = (k & 15) * 4;
            union { short h[4]; int2 v; } u;
            #pragma unroll
            for (int j = 0; j < 4; j++) {
                int mm = c4 + j;
                float v = 0.1f * t[mm][rr] + ((n0 + rr) == (m0 + mm) ? 1.0f : 0.0f);
                u.h[j] = f2bf(v);
            }
            *(int2*)&Ad[(size_t)(n0 + rr) * Nn + m0 + c4] = u.v;
        }
        return;
    }
    if (bid < 2496) {                       // wqT[n][k] = bf16(wq[k][n])
        int idx = bid - 2304;
        const int n0 = (idx % 24) * 64, k0 = (idx / 24) * 64;
        #pragma unroll
        for (int i = 0; i < 4; i++) {
            int k = i * 256 + tid;
            int r = k >> 4, c4 = (k & 15) * 4;
            *(float4*)&t[r][c4] = *(const float4*)&wq[(size_t)(k0 + r) * 1536 + n0 + c4];
        }
        __syncthreads();
        #pragma unroll
        for (int i = 0; i < 4; i++) {
            int k = i * 256 + tid;
            int rr = k >> 4, c4 = (k & 15) * 4;
            union { short h[4]; int2 v; } u;
            #pragma unroll
            for (int j = 0; j < 4; j++) u.h[j] = f2bf(t[c4 + j][rr]);
            *(int2*)&wqT[(size_t)(n0 + rr) * 512 + k0 + c4] = u.v;
        }
        return;
    }
    {                                        // woT hi/lo
        int idx = bid - 2496;
        const int n0 = (idx & 7) * 64, k0 = (idx >> 3) * 64;
        #pragma unroll
        for (int i = 0; i < 4; i++) {
            int k = i * 256 + tid;
            int r = k >> 4, c4 = (k & 15) * 4;
            *(float4*)&t[r][c4] = *(const float4*)&wo[(size_t)(k0 + r) * 512 + n0 + c4];
        }
        __syncthreads();
        #pragma unroll
        for (int i = 0; i < 4; i++) {
            int k = i * 256 + tid;
            int rr = k >> 4, c4 = (k & 15) * 4;
            union { short h[4]; int2 v; } uh, ul;
            #pragma unroll
            for (int j = 0; j < 4; j++) {
                float v = t[c4 + j][rr];
                short hi = f2bf(v);
                uh.h[j] = hi;
                ul.h[j] = f2bf(v - bf2f(hi));
            }
            *(int2*)&whi[(size_t)(n0 + rr) * 512 + k0 + c4] = uh.v;
            *(int2*)&wlo[(size_t)(n0 + rr) * 512 + k0 + c4] = ul.v;
        }
    }
}

// ---------------------------------------------------------------------------
// GEMM1: qkv = xb[8192][512] @ wqT^T, relu+eps on cols<1024.
// Epilogue: LDS transpose, writes qT/kT/vT[b][c][m] bf16 (B-operand layout).
// ---------------------------------------------------------------------------
__global__ __launch_bounds__(256)
void gemm_qkv(const short* __restrict__ xb, const short* __restrict__ wqT,
              short* __restrict__ qT, short* __restrict__ kT,
              short* __restrict__ vT) {
    __shared__ short smem[17408];             // 34816 B
    short* As = smem;
    short* Bs = smem + 8192;

    const int tid = threadIdx.x;
    const int m0 = blockIdx.y * 128;
    const int n0 = blockIdx.x * 128;
    const int wave = tid >> 6, lane = tid & 63;
    const int quad = lane >> 4, l16 = lane & 15;
    const int wm = (wave >> 1) * 64, wn = (wave & 1) * 64;

    floatx4 acc[4][4];
    #pragma unroll
    for (int i = 0; i < 4; i++)
        #pragma unroll
        for (int j = 0; j < 4; j++) acc[i][j] = (floatx4){0.f, 0.f, 0.f, 0.f};

    const short* Ab = xb  + (size_t)m0 * 512;
    const short* Bb = wqT + (size_t)n0 * 512;

    for (int k0 = 0; k0 < 512; k0 += 64) {
        __syncthreads();
        stage_tile(As, Ab + k0, 512, tid, 8, 1024);
        stage_tile(Bs, Bb + k0, 512, tid, 8, 1024);
        __syncthreads();
        #pragma unroll
        for (int kh = 0; kh < 2; kh++) {
            short8 a[4], b[4];
            #pragma unroll
            for (int i = 0; i < 4; i++) a[i] = fragT(As, 8, wm + i * 16 + l16, kh * 4 + quad);
            #pragma unroll
            for (int i = 0; i < 4; i++) b[i] = fragT(Bs, 8, wn + i * 16 + l16, kh * 4 + quad);
            #pragma unroll
            for (int mi = 0; mi < 4; mi++)
                #pragma unroll
                for (int ni = 0; ni < 4; ni++)
                    acc[mi][ni] = __builtin_amdgcn_mfma_f32_16x16x32_bf16(
                        a[mi], b[ni], acc[mi][ni], 0, 0, 0);
        }
    }

    __syncthreads();
    short* Tt = smem;                          // [128 cols][136]
    const int doRelu = (n0 < 1024);
    #pragma unroll
    for (int mi = 0; mi < 4; mi++)
        #pragma unroll
        for (int ni = 0; ni < 4; ni++)
            #pragma unroll
            for (int r = 0; r < 4; r++) {
                float v = acc[mi][ni][r];
                if (doRelu) v = fmaxf(v, 0.0f) + EPSF;
                int nl = wn + ni * 16 + l16;
                int ml = wm + mi * 16 + quad * 4 + r;
                Tt[nl * 136 + ml] = f2bf(v);
            }
    __syncthreads();

    const int b = m0 >> 10, m_in = m0 & 1023;
    int row = tid >> 1, half = tid & 1;
    int cg = n0 + row;
    int part = cg >> 9, ci = cg & 511;
    short* base = (part == 0) ? qT : (part == 1) ? kT : vT;
    short* dst = base + ((size_t)b * 512 + ci) * 1024 + m_in + half * 64;
    const short* srcl = &Tt[row * 136 + half * 64];
    #pragma unroll
    for (int i = 0; i < 8; i++)     // 8 x int4 = full 64-short half-row
        *(int4*)&dst[i * 8] = *(const int4*)&srcl[i * 8];
}

// ---------------------------------------------------------------------------
// Diffusion GEMM: qd[b][n][c] = sum_m Ad[n][m] * q[b][m][c]  (BT = qT)
// ---------------------------------------------------------------------------
__global__ __launch_bounds__(256)
void gemm_diff(const short* __restrict__ Ad, const short* __restrict__ qT,
               const short* __restrict__ kT, short* __restrict__ qd,
               short* __restrict__ kd) {
    __shared__ short smem[16384];
    short* As = smem;
    short* Bs = smem + 8192;

    const int tid = threadIdx.x;
    const int z = blockIdx.z, b = z >> 1, part = z & 1;
    const short* BTb = (part ? kT : qT) + (size_t)b * 512 * 1024;
    short* outb = (part ? kd : qd) + (size_t)b * 1024 * 512;

    const int r0 = blockIdx.y * 128;
    const int c0 = blockIdx.x * 128;
    const int wave = tid >> 6, lane = tid & 63;
    const int quad = lane >> 4, l16 = lane & 15;
    const int wm = (wave >> 1) * 64, wn = (wave & 1) * 64;

    floatx4 acc[4][4];
    #pragma unroll
    for (int i = 0; i < 4; i++)
        #pragma unroll
        for (int j = 0; j < 4; j++) acc[i][j] = (floatx4){0.f, 0.f, 0.f, 0.f};

    const short* Ab = Ad  + (size_t)r0 * 1024;
    const short* Bb = BTb + (size_t)c0 * 1024;

    for (int k0 = 0; k0 < 1024; k0 += 64) {
        __syncthreads();
        stage_tile(As, Ab + k0, 1024, tid, 8, 1024);
        stage_tile(Bs, Bb + k0, 1024, tid, 8, 1024);
        __syncthreads();
        #pragma unroll
        for (int kh = 0; kh < 2; kh++) {
            short8 a[4], b2[4];
            #pragma unroll
            for (int i = 0; i < 4; i++) a[i]  = fragT(As, 8, wm + i * 16 + l16, kh * 4 + quad);
            #pragma unroll
            for (int i = 0; i < 4; i++) b2[i] = fragT(Bs, 8, wn + i * 16 + l16, kh * 4 + quad);
            #pragma unroll
            for (int mi = 0; mi < 4; mi++)
                #pragma unroll
                for (int ni = 0; ni < 4; ni++)
                    acc[mi][ni] = __builtin_amdgcn_mfma_f32_16x16x32_bf16(
                        a[mi], b2[ni], acc[mi][ni], 0, 0, 0);
        }
    }

    #pragma unroll
    for (int mi = 0; mi < 4; mi++)
        #pragma unroll
        for (int r = 0; r < 4; r++) {
            int n = r0 + wm + mi * 16 + quad * 4 + r;
            #pragma unroll
            for (int ni = 0; ni < 4; ni++) {
                int c = c0 + wn + ni * 16 + l16;
                outb[(size_t)n * 512 + c] = f2bf(acc[mi][ni][r]);
            }
        }
}

// ---------------------------------------------------------------------------
// Masked linear attention (MFMA bf16, flash-style).
// m-chunk = 128 (8 chunks -> half the barrier drains of r5), processed as
// two 64-halves; ss reused across halves (wave-private rows, no barrier).
// Mask read direct from global (fp32, L2/L3-resident). LDS 48 KB.
// ---------------------------------------------------------------------------
__global__ __launch_bounds__(256)
void attn_mfma(const short* __restrict__ qd, const short* __restrict__ kd,
               const short* __restrict__ vTg, const float* __restrict__ mask,
               short* __restrict__ ahi, short* __restrict__ alo) {
    __shared__ short qs[4096];   // 64 rows x 64 c   (8 chunks)
    __shared__ short ks[8192];   // 128 m-rows x 64 c (8 chunks)
    __shared__ short vt[8192];   // 64 d-rows x 128 m (16 chunks)
    __shared__ short ss[4096];   // 64 n-rows x 64 m  (8 chunks)

    const int tid = threadIdx.x;
    const int bh = blockIdx.y;
    const int b = bh >> 3, h = bh & 7;
    const int n0 = blockIdx.x * 64;

    const int wave = tid >> 6, lane = tid & 63;
    const int quad = lane >> 4, l16 = lane & 15;

    const short* Qb = qd + ((size_t)b * Nn + n0) * Cc + h * Dd;        // stride Cc
    const short* Kb = kd + (size_t)b * Nn * Cc + h * Dd;               // stride Cc
    const short* Vb = vTg + ((size_t)b * Cc + h * Dd) * Nn;            // stride Nn
    const float* Mb = mask + (size_t)n0 * Nn;

    stage_tile(qs, Qb, Cc, tid, 8, 512);
    __syncthreads();                          // qs resident (vmcnt drained)
    const short8 a0 = fragT(qs, 8, wave * 16 + l16, quad);
    const short8 a1 = fragT(qs, 8, wave * 16 + l16, 4 + quad);

    float dreg[4] = {0.f, 0.f, 0.f, 0.f};
    floatx4 nacc[4];
    #pragma unroll
    for (int i = 0; i < 4; i++) nacc[i] = (floatx4){0.f, 0.f, 0.f, 0.f};

    for (int m0 = 0; m0 < Nn; m0 += 128) {
        __syncthreads();                      // prior chunk's ks/vt readers done
        stage_tile(ks, Kb + (size_t)m0 * Cc, Cc, tid, 8, 1024);   // K rows m0..+128
        stage_tile(vt, Vb + m0, Nn, tid, 16, 1024);               // V^T cols m0..+128
        __syncthreads();                      // staged data visible

        #pragma unroll
        for (int half = 0; half < 2; half++) {
            const int mh = half * 64;
            // phase A: S = (Q K^T) * mask (fp32) -> ss (bf16), denom acc
            #pragma unroll
            for (int mt = 0; mt < 4; mt++) {
                const short8 b0 = fragT(ks, 8, mh + mt * 16 + l16, quad);
                const short8 b1 = fragT(ks, 8, mh + mt * 16 + l16, 4 + quad);
                floatx4 s = (floatx4){0.f, 0.f, 0.f, 0.f};
                s = __builtin_amdgcn_mfma_f32_16x16x32_bf16(a0, b0, s, 0, 0, 0);
                s = __builtin_amdgcn_mfma_f32_16x16x32_bf16(a1, b1, s, 0, 0, 0);
                #pragma unroll
                for (int r = 0; r < 4; r++) {
                    int rl = wave * 16 + quad * 4 + r;
                    float mv = Mb[(size_t)rl * Nn + m0 + mh + mt * 16 + l16];
                    float sv = s[r] * mv;
                    dreg[r] += sv;
                    ss[swz8(rl, mt * 16 + l16)] = f2bf(sv);
                }
            }
            // no barrier: each wave reads exactly the ss rows it wrote
            // (within-wave in-order LDS + compiler lgkmcnt suffices)

            // phase B: num += S @ V (v-frag k-chunks offset by this half)
            const short8 p0 = fragT(ss, 8, wave * 16 + l16, quad);
            const short8 p1 = fragT(ss, 8, wave * 16 + l16, 4 + quad);
            #pragma unroll
            for (int dt = 0; dt < 4; dt++) {
                const short8 v0 = fragT(vt, 16, dt * 16 + l16, half * 8 + quad);
                const short8 v1 = fragT(vt, 16, dt * 16 + l16, half * 8 + 4 + quad);
                nacc[dt] = __builtin_amdgcn_mfma_f32_16x16x32_bf16(p0, v0, nacc[dt], 0, 0, 0);
                nacc[dt] = __builtin_amdgcn_mfma_f32_16x16x32_bf16(p1, v1, nacc[dt], 0, 0, 0);
            }
        }
    }

    #pragma unroll
    for (int r = 0; r < 4; r++) {
        #pragma unroll
        for (int off = 1; off < 16; off <<= 1)
            dreg[r] += __shfl_xor(dreg[r], off, 64);
    }

    #pragma unroll
    for (int r = 0; r < 4; r++) {
        int n = n0 + wave * 16 + quad * 4 + r;
        float zr = 1.0f / (dreg[r] + EPSF);
        #pragma unroll
        for (int dt = 0; dt < 4; dt++) {
            float val = nacc[dt][r] * zr;
            short hi = f2bf(val);
            short lo = f2bf(val - bf2f(hi));
            size_t o = ((size_t)b * Nn + n) * Cc + h * Dd + dt * 16 + l16;
            ahi[o] = hi;
            alo[o] = lo;
        }
    }
}

// ---------------------------------------------------------------------------
// Output GEMM (bf16x3 split): out = Ahi@Whi + Ahi@Wlo + Alo@Whi + bias (fp32)
// 64x128 tile -> 512 blocks (2/CU resident; was 256 = 1/CU unhidden drains).
// ---------------------------------------------------------------------------
__global__ __launch_bounds__(256)
void gemm_out(const short* __restrict__ ahi, const short* __restrict__ alo,
              const short* __restrict__ whi, const short* __restrict__ wlo,
              const float* __restrict__ bias, float* __restrict__ out) {
    __shared__ short smem[24576];      // 48 KB
    short* Ah = smem;                  // 64x64
    short* Al = smem + 4096;
    short* Bh = smem + 8192;           // 128x64
    short* Bl = smem + 16384;

    const int tid = threadIdx.x;
    const int m0 = blockIdx.y * 64;
    const int n0 = blockIdx.x * 128;
    const int wave = tid >> 6, lane = tid & 63;
    const int quad = lane >> 4, l16 = lane & 15;
    const int wm = (wave >> 1) * 32, wn = (wave & 1) * 64;

    floatx4 acc[2][4];
    #pragma unroll
    for (int i = 0; i < 2; i++)
        #pragma unroll
        for (int j = 0; j < 4; j++) acc[i][j] = (floatx4){0.f, 0.f, 0.f, 0.f};

    const short* Ahb = ahi + (size_t)m0 * 512;
    const short* Alb = alo + (size_t)m0 * 512;
    const short* Bhb = whi + (size_t)n0 * 512;
    const short* Blb = wlo + (size_t)n0 * 512;

    for (int k0 = 0; k0 < 512; k0 += 64) {
        __syncthreads();
        stage_tile(Ah, Ahb + k0, 512, tid, 8, 512);
        stage_tile(Al, Alb + k0, 512, tid, 8, 512);
        stage_tile(Bh, Bhb + k0, 512, tid, 8, 1024);
        stage_tile(Bl, Blb + k0, 512, tid, 8, 1024);
        __syncthreads();
        #pragma unroll
        for (int kh = 0; kh < 2; kh++) {
            short8 ah[2], al[2], bh[4], bl[4];
            #pragma unroll
            for (int i = 0; i < 2; i++) {
                ah[i] = fragT(Ah, 8, wm + i * 16 + l16, kh * 4 + quad);
                al[i] = fragT(Al, 8, wm + i * 16 + l16, kh * 4 + quad);
            }
            #pragma unroll
            for (int i = 0; i < 4; i++) {
                bh[i] = fragT(Bh, 8, wn + i * 16 + l16, kh * 4 + quad);
                bl[i] = fragT(Bl, 8, wn + i * 16 + l16, kh * 4 + quad);
            }
            #pragma unroll
            for (int mi = 0; mi < 2; mi++)
                #pragma unroll
                for (int ni = 0; ni < 4; ni++) {
                    acc[mi][ni] = __builtin_amdgcn_mfma_f32_16x16x32_bf16(
                        ah[mi], bh[ni], acc[mi][ni], 0, 0, 0);
                    acc[mi][ni] = __builtin_amdgcn_mfma_f32_16x16x32_bf16(
                        ah[mi], bl[ni], acc[mi][ni], 0, 0, 0);
                    acc[mi][ni] = __builtin_amdgcn_mfma_f32_16x16x32_bf16(
                        al[mi], bh[ni], acc[mi][ni], 0, 0, 0);
                }
        }
    }

    #pragma unroll
    for (int mi = 0; mi < 2; mi++)
        #pragma unroll
        for (int r = 0; r < 4; r++) {
            int m = m0 + wm + mi * 16 + quad * 4 + r;
            #pragma unroll
            for (int ni = 0; ni < 4; ni++) {
                int n = n0 + wn + ni * 16 + l16;
                out[(size_t)m * 512 + n] = acc[mi][ni][r] + bias[n];
            }
        }
}

// ---------------------------------------------------------------------------
extern "C" void kernel_launch(void* const* d_in, const int* in_sizes, int n_in,
                              void* d_out, int out_size, void* d_ws, size_t ws_size,
                              hipStream_t stream) {
    const float* x     = (const float*)d_in[0];
    const float* mask  = (const float*)d_in[1];
    const float* w_qkv = (const float*)d_in[2];
    const float* w_out = (const float*)d_in[3];
    const float* b_out = (const float*)d_in[4];
    float* out = (float*)d_out;

    char* p = (char*)d_ws;
    short* xb  = (short*)p; p += 8388608;      // [8192][512]
    short* wqT = (short*)p; p += 1572864;      // [1536][512]
    short* Ad  = (short*)p; p += 2097152;      // [1024][1024]
    short* whi = (short*)p; p += 524288;       // [512][512]
    short* wlo = (short*)p; p += 524288;
    short* qT  = (short*)p; p += 8388608;      // [b][512][1024]
    short* kT  = (short*)p; p += 8388608;
    short* vT  = (short*)p; p += 8388608;
    short* qd  = (short*)p; p += 8388608;      // [b][1024][512]
    short* kd  = (short*)p; p += 8388608;
    short* ahi = (short*)p; p += 8388608;      // [8192][512]
    short* alo = (short*)p; p += 8388608;

    dim3 blk(256);

    prep_all  <<<2560, blk, 0, stream>>>(x, mask, w_qkv, w_out,
                                         xb, Ad, wqT, whi, wlo);
    gemm_qkv  <<<dim3(12, 64), blk, 0, stream>>>(xb, wqT, qT, kT, vT);
    gemm_diff <<<dim3(4, 8, 16), blk, 0, stream>>>(Ad, qT, kT, qd, kd);
    attn_mfma <<<dim3(16, 64), blk, 0, stream>>>(qd, kd, vT, mask, ahi, alo);
    gemm_out  <<<dim3(4, 128), blk, 0, stream>>>(ahi, alo, whi, wlo, b_out, out);
}

// Round 7
// 184.847 us; speedup vs baseline: 8.7753x; 1.0179x over previous
//
#include <hip/hip_runtime.h>
#include <cstddef>

// Problem constants
#define Bsz 8
#define Nn  1024
#define Cc  512
#define Hh  8
#define Dd  64
#define EPSF 1e-6f

typedef __attribute__((ext_vector_type(8))) short short8;   // 8 bf16 (4 VGPRs)
typedef __attribute__((ext_vector_type(4))) float floatx4;  // MFMA accumulator

// round-to-nearest-even fp32 -> bf16 (bit pattern in a short)
static __device__ __forceinline__ short f2bf(float f) {
    union { float f; unsigned u; } v; v.f = f;
    unsigned r = (v.u + 0x7FFFu + ((v.u >> 16) & 1u)) >> 16;
    return (short)r;
}
static __device__ __forceinline__ float bf2f(short s) {
    union { unsigned u; float f; } v; v.u = ((unsigned)(unsigned short)s) << 16;
    return v.f;
}

// ---------------------------------------------------------------------------
// XOR-swizzled LDS tiles, linear 16B slots (lane-linear => global_load_lds ok).
// Tile = ROWS x (CHUNKS*8) bf16.  Slot s holds row r=s/CHUNKS, global chunk
// (s%CHUNKS)^(r&7).  Fragment read for row r, logical chunk lc is slot
// r*CHUNKS + (lc^(r&7)) -> bank-balanced ds_read_b128.
// ---------------------------------------------------------------------------
#define GLOAD_LDS16(gp, lp)                                              \
    __builtin_amdgcn_global_load_lds(                                    \
        (const __attribute__((address_space(1))) void*)(gp),             \
        (__attribute__((address_space(3))) void*)(lp), 16, 0, 0)

static __device__ __forceinline__
void stage_tile(short* __restrict__ lds, const short* __restrict__ src,
                int ldsrc, int tid, int CHUNKS, int SLOTS) {
    #pragma unroll
    for (int s = tid; s < SLOTS; s += 256) {
        int r = s / CHUNKS, cs = s % CHUNKS;
        int gc = cs ^ (r & 7);
        GLOAD_LDS16(&src[(size_t)r * ldsrc + gc * 8], &lds[s * 8]);
    }
}
static __device__ __forceinline__
short8 fragT(const short* __restrict__ lds, int CHUNKS, int r, int lc) {
    return *(const short8*)&lds[(r * CHUNKS + (lc ^ (r & 7))) * 8];
}
static __device__ __forceinline__ int swz8(int r, int c) {   // CHUNKS=8 offset
    return (r * 8 + (((c) >> 3) ^ (r & 7))) * 8 + ((c) & 7);
}

// ---------------------------------------------------------------------------
// Merged prep: blocks [0,2048) cvt x->bf16; [2048,2304) diffusion operator;
// [2304,2496) w_qkv^T; [2496,2560) w_out^T hi/lo split.
// ---------------------------------------------------------------------------
__global__ __launch_bounds__(256)
void prep_all(const float* __restrict__ x, const float* __restrict__ mask,
              const float* __restrict__ wq, const float* __restrict__ wo,
              short* __restrict__ xb, short* __restrict__ Ad,
              short* __restrict__ wqT, short* __restrict__ whi,
              short* __restrict__ wlo) {
    __shared__ float t[64][65];
    const int tid = threadIdx.x;
    const int bid = blockIdx.x;

    if (bid < 2048) {                       // x -> bf16, 8 elems/thread
        int idx = bid * 256 + tid;
        const float* s = &x[(size_t)idx * 8];
        union { short h[8]; int4 v; } u;
        #pragma unroll
        for (int j = 0; j < 8; j++) u.h[j] = f2bf(s[j]);
        *(int4*)&xb[(size_t)idx * 8] = u.v;
        return;
    }
    if (bid < 2304) {                       // Ad[n][m] = bf16(I + 0.1*mask^T)
        int idx = bid - 2048;
        const int n0 = (idx & 15) * 64, m0 = (idx >> 4) * 64;
        #pragma unroll
        for (int i = 0; i < 4; i++) {
            int k = i * 256 + tid;
            int r = k >> 4, c4 = (k & 15) * 4;
            *(float4*)&t[r][c4] = *(const float4*)&mask[(size_t)(m0 + r) * Nn + n0 + c4];
        }
        __syncthreads();
        #pragma unroll
        for (int i = 0; i < 4; i++) {
            int k = i * 256 + tid;
            int rr = k >> 4, c4 = (k & 15) * 4;
            union { short h[4]; int2 v; } u;
            #pragma unroll
            for (int j = 0; j < 4; j++) {
                int mm = c4 + j;
                float v = 0.1f * t[mm][rr] + ((n0 + rr) == (m0 + mm) ? 1.0f : 0.0f);
                u.h[j] = f2bf(v);
            }
            *(int2*)&Ad[(size_t)(n0 + rr) * Nn + m0 + c4] = u.v;
        }
        return;
    }
    if (bid < 2496) {                       // wqT[n][k] = bf16(wq[k][n])
        int idx = bid - 2304;
        const int n0 = (idx % 24) * 64, k0 = (idx / 24) * 64;
        #pragma unroll
        for (int i = 0; i < 4; i++) {
            int k = i * 256 + tid;
            int r = k >> 4, c4 = (k & 15) * 4;
            *(float4*)&t[r][c4] = *(const float4*)&wq[(size_t)(k0 + r) * 1536 + n0 + c4];
        }
        __syncthreads();
        #pragma unroll
        for (int i = 0; i < 4; i++) {
            int k = i * 256 + tid;
            int rr = k >> 4, c4 = (k & 15) * 4;
            union { short h[4]; int2 v; } u;
            #pragma unroll
            for (int j = 0; j < 4; j++) u.h[j] = f2bf(t[c4 + j][rr]);
            *(int2*)&wqT[(size_t)(n0 + rr) * 512 + k0 + c4] = u.v;
        }
        return;
    }
    {                                        // woT hi/lo
        int idx = bid - 2496;
        const int n0 = (idx & 7) * 64, k0 = (idx >> 3) * 64;
        #pragma unroll
        for (int i = 0; i < 4; i++) {
            int k = i * 256 + tid;
            int r = k >> 4, c4 = (k & 15) * 4;
            *(float4*)&t[r][c4] = *(const float4*)&wo[(size_t)(k0 + r) * 512 + n0 + c4];
        }
        __syncthreads();
        #pragma unroll
        for (int i = 0; i < 4; i++) {
            int k = i * 256 + tid;
            int rr = k >> 4, c4 = (k & 15) * 4;
            union { short h[4]; int2 v; } uh, ul;
            #pragma unroll
            for (int j = 0; j < 4; j++) {
                float v = t[c4 + j][rr];
                short hi = f2bf(v);
                uh.h[j] = hi;
                ul.h[j] = f2bf(v - bf2f(hi));
            }
            *(int2*)&whi[(size_t)(n0 + rr) * 512 + k0 + c4] = uh.v;
            *(int2*)&wlo[(size_t)(n0 + rr) * 512 + k0 + c4] = ul.v;
        }
    }
}

// ---------------------------------------------------------------------------
// GEMM1: qkv = xb[8192][512] @ wqT^T, relu+eps on cols<1024.
// Epilogue: LDS transpose, writes qT/kT/vT[b][c][m] bf16 (B-operand layout).
// ---------------------------------------------------------------------------
__global__ __launch_bounds__(256)
void gemm_qkv(const short* __restrict__ xb, const short* __restrict__ wqT,
              short* __restrict__ qT, short* __restrict__ kT,
              short* __restrict__ vT) {
    __shared__ short smem[17408];             // 34816 B
    short* As = smem;
    short* Bs = smem + 8192;

    const int tid = threadIdx.x;
    const int m0 = blockIdx.y * 128;
    const int n0 = blockIdx.x * 128;
    const int wave = tid >> 6, lane = tid & 63;
    const int quad = lane >> 4, l16 = lane & 15;
    const int wm = (wave >> 1) * 64, wn = (wave & 1) * 64;

    floatx4 acc[4][4];
    #pragma unroll
    for (int i = 0; i < 4; i++)
        #pragma unroll
        for (int j = 0; j < 4; j++) acc[i][j] = (floatx4){0.f, 0.f, 0.f, 0.f};

    const short* Ab = xb  + (size_t)m0 * 512;
    const short* Bb = wqT + (size_t)n0 * 512;

    for (int k0 = 0; k0 < 512; k0 += 64) {
        __syncthreads();
        stage_tile(As, Ab + k0, 512, tid, 8, 1024);
        stage_tile(Bs, Bb + k0, 512, tid, 8, 1024);
        __syncthreads();
        #pragma unroll
        for (int kh = 0; kh < 2; kh++) {
            short8 a[4], b[4];
            #pragma unroll
            for (int i = 0; i < 4; i++) a[i] = fragT(As, 8, wm + i * 16 + l16, kh * 4 + quad);
            #pragma unroll
            for (int i = 0; i < 4; i++) b[i] = fragT(Bs, 8, wn + i * 16 + l16, kh * 4 + quad);
            #pragma unroll
            for (int mi = 0; mi < 4; mi++)
                #pragma unroll
                for (int ni = 0; ni < 4; ni++)
                    acc[mi][ni] = __builtin_amdgcn_mfma_f32_16x16x32_bf16(
                        a[mi], b[ni], acc[mi][ni], 0, 0, 0);
        }
    }

    __syncthreads();
    short* Tt = smem;                          // [128 cols][136]
    const int doRelu = (n0 < 1024);
    #pragma unroll
    for (int mi = 0; mi < 4; mi++)
        #pragma unroll
        for (int ni = 0; ni < 4; ni++)
            #pragma unroll
            for (int r = 0; r < 4; r++) {
                float v = acc[mi][ni][r];
                if (doRelu) v = fmaxf(v, 0.0f) + EPSF;
                int nl = wn + ni * 16 + l16;
                int ml = wm + mi * 16 + quad * 4 + r;
                Tt[nl * 136 + ml] = f2bf(v);
            }
    __syncthreads();

    const int b = m0 >> 10, m_in = m0 & 1023;
    int row = tid >> 1, half = tid & 1;
    int cg = n0 + row;
    int part = cg >> 9, ci = cg & 511;
    short* base = (part == 0) ? qT : (part == 1) ? kT : vT;
    short* dst = base + ((size_t)b * 512 + ci) * 1024 + m_in + half * 64;
    const short* srcl = &Tt[row * 136 + half * 64];
    #pragma unroll
    for (int i = 0; i < 8; i++)     // 8 x int4 = full 64-short half-row
        *(int4*)&dst[i * 8] = *(const int4*)&srcl[i * 8];
}

// ---------------------------------------------------------------------------
// Diffusion GEMM: qd[b][n][c] = sum_m Ad[n][m] * q[b][m][c]  (BT = qT)
// ---------------------------------------------------------------------------
__global__ __launch_bounds__(256)
void gemm_diff(const short* __restrict__ Ad, const short* __restrict__ qT,
               const short* __restrict__ kT, short* __restrict__ qd,
               short* __restrict__ kd) {
    __shared__ short smem[16384];
    short* As = smem;
    short* Bs = smem + 8192;

    const int tid = threadIdx.x;
    const int z = blockIdx.z, b = z >> 1, part = z & 1;
    const short* BTb = (part ? kT : qT) + (size_t)b * 512 * 1024;
    short* outb = (part ? kd : qd) + (size_t)b * 1024 * 512;

    const int r0 = blockIdx.y * 128;
    const int c0 = blockIdx.x * 128;
    const int wave = tid >> 6, lane = tid & 63;
    const int quad = lane >> 4, l16 = lane & 15;
    const int wm = (wave >> 1) * 64, wn = (wave & 1) * 64;

    floatx4 acc[4][4];
    #pragma unroll
    for (int i = 0; i < 4; i++)
        #pragma unroll
        for (int j = 0; j < 4; j++) acc[i][j] = (floatx4){0.f, 0.f, 0.f, 0.f};

    const short* Ab = Ad  + (size_t)r0 * 1024;
    const short* Bb = BTb + (size_t)c0 * 1024;

    for (int k0 = 0; k0 < 1024; k0 += 64) {
        __syncthreads();
        stage_tile(As, Ab + k0, 1024, tid, 8, 1024);
        stage_tile(Bs, Bb + k0, 1024, tid, 8, 1024);
        __syncthreads();
        #pragma unroll
        for (int kh = 0; kh < 2; kh++) {
            short8 a[4], b2[4];
            #pragma unroll
            for (int i = 0; i < 4; i++) a[i]  = fragT(As, 8, wm + i * 16 + l16, kh * 4 + quad);
            #pragma unroll
            for (int i = 0; i < 4; i++) b2[i] = fragT(Bs, 8, wn + i * 16 + l16, kh * 4 + quad);
            #pragma unroll
            for (int mi = 0; mi < 4; mi++)
                #pragma unroll
                for (int ni = 0; ni < 4; ni++)
                    acc[mi][ni] = __builtin_amdgcn_mfma_f32_16x16x32_bf16(
                        a[mi], b2[ni], acc[mi][ni], 0, 0, 0);
        }
    }

    #pragma unroll
    for (int mi = 0; mi < 4; mi++)
        #pragma unroll
        for (int r = 0; r < 4; r++) {
            int n = r0 + wm + mi * 16 + quad * 4 + r;
            #pragma unroll
            for (int ni = 0; ni < 4; ni++) {
                int c = c0 + wn + ni * 16 + l16;
                outb[(size_t)n * 512 + c] = f2bf(acc[mi][ni][r]);
            }
        }
}

// ---------------------------------------------------------------------------
// Masked linear attention (MFMA bf16, flash-style), v3:
// 128 q-rows per block (wave owns 32 = two 16-row tiles), m-chunk 64.
// K/V frags shared across both n-tiles (2x LDS-read efficiency); staging
// per q-row halved.  Grid 512 = exactly 2 blocks/CU, single round
// (48 KB LDS -> 3/CU capacity).  Mask read direct from global (fp32).
// ---------------------------------------------------------------------------
__global__ __launch_bounds__(256)
void attn_mfma(const short* __restrict__ qd, const short* __restrict__ kd,
               const short* __restrict__ vTg, const float* __restrict__ mask,
               short* __restrict__ ahi, short* __restrict__ alo) {
    __shared__ short qs[8192];   // 128 n-rows x 64 c (8 chunks)
    __shared__ short ks[4096];   //  64 m-rows x 64 c (8 chunks)
    __shared__ short vt[4096];   //  64 d-rows x 64 m (8 chunks)
    __shared__ short ss[8192];   // 128 n-rows x 64 m (8 chunks, wave-private rows)

    const int tid = threadIdx.x;
    const int bh = blockIdx.y;
    const int b = bh >> 3, h = bh & 7;
    const int n0 = blockIdx.x * 128;

    const int wave = tid >> 6, lane = tid & 63;
    const int quad = lane >> 4, l16 = lane & 15;

    const short* Qb = qd + ((size_t)b * Nn + n0) * Cc + h * Dd;        // stride Cc
    const short* Kb = kd + (size_t)b * Nn * Cc + h * Dd;               // stride Cc
    const short* Vb = vTg + ((size_t)b * Cc + h * Dd) * Nn;            // stride Nn
    const float* Mb = mask + (size_t)n0 * Nn;

    stage_tile(qs, Qb, Cc, tid, 8, 1024);
    __syncthreads();                          // qs resident (vmcnt drained)
    short8 aT[2][2];
    #pragma unroll
    for (int t = 0; t < 2; t++) {
        aT[t][0] = fragT(qs, 8, wave * 32 + t * 16 + l16, quad);
        aT[t][1] = fragT(qs, 8, wave * 32 + t * 16 + l16, 4 + quad);
    }

    float dreg[2][4] = {};
    floatx4 nacc[2][4];
    #pragma unroll
    for (int t = 0; t < 2; t++)
        #pragma unroll
        for (int i = 0; i < 4; i++) nacc[t][i] = (floatx4){0.f, 0.f, 0.f, 0.f};

    for (int m0 = 0; m0 < Nn; m0 += 64) {
        __syncthreads();                      // prior chunk's ks/vt readers done
        stage_tile(ks, Kb + (size_t)m0 * Cc, Cc, tid, 8, 512);
        stage_tile(vt, Vb + m0, Nn, tid, 8, 512);
        __syncthreads();                      // staged data visible

        // phase A: S = (Q K^T) * mask (fp32) -> ss (bf16), denom acc.
        // K-frags shared across both n-tiles.
        #pragma unroll
        for (int mt = 0; mt < 4; mt++) {
            const short8 b0 = fragT(ks, 8, mt * 16 + l16, quad);
            const short8 b1 = fragT(ks, 8, mt * 16 + l16, 4 + quad);
            #pragma unroll
            for (int t = 0; t < 2; t++) {
                floatx4 s = (floatx4){0.f, 0.f, 0.f, 0.f};
                s = __builtin_amdgcn_mfma_f32_16x16x32_bf16(aT[t][0], b0, s, 0, 0, 0);
                s = __builtin_amdgcn_mfma_f32_16x16x32_bf16(aT[t][1], b1, s, 0, 0, 0);
                #pragma unroll
                for (int r = 0; r < 4; r++) {
                    int rl = wave * 32 + t * 16 + quad * 4 + r;
                    float mv = Mb[(size_t)rl * Nn + m0 + mt * 16 + l16];
                    float sv = s[r] * mv;
                    dreg[t][r] += sv;
                    ss[swz8(rl, mt * 16 + l16)] = f2bf(sv);
                }
            }
        }
        // no barrier: each wave reads exactly the ss rows it wrote
        // (within-wave in-order LDS + compiler lgkmcnt suffices)

        // phase B: num += S @ V.  V-frags shared across both n-tiles.
        short8 p[2][2];
        #pragma unroll
        for (int t = 0; t < 2; t++) {
            p[t][0] = fragT(ss, 8, wave * 32 + t * 16 + l16, quad);
            p[t][1] = fragT(ss, 8, wave * 32 + t * 16 + l16, 4 + quad);
        }
        #pragma unroll
        for (int dt = 0; dt < 4; dt++) {
            const short8 v0 = fragT(vt, 8, dt * 16 + l16, quad);
            const short8 v1 = fragT(vt, 8, dt * 16 + l16, 4 + quad);
            #pragma unroll
            for (int t = 0; t < 2; t++) {
                nacc[t][dt] = __builtin_amdgcn_mfma_f32_16x16x32_bf16(p[t][0], v0, nacc[t][dt], 0, 0, 0);
                nacc[t][dt] = __builtin_amdgcn_mfma_f32_16x16x32_bf16(p[t][1], v1, nacc[t][dt], 0, 0, 0);
            }
        }
    }

    #pragma unroll
    for (int t = 0; t < 2; t++)
        #pragma unroll
        for (int r = 0; r < 4; r++) {
            #pragma unroll
            for (int off = 1; off < 16; off <<= 1)
                dreg[t][r] += __shfl_xor(dreg[t][r], off, 64);
        }

    #pragma unroll
    for (int t = 0; t < 2; t++)
        #pragma unroll
        for (int r = 0; r < 4; r++) {
            int n = n0 + wave * 32 + t * 16 + quad * 4 + r;
            float zr = 1.0f / (dreg[t][r] + EPSF);
            #pragma unroll
            for (int dt = 0; dt < 4; dt++) {
                float val = nacc[t][dt][r] * zr;
                short hi = f2bf(val);
                short lo = f2bf(val - bf2f(hi));
                size_t o = ((size_t)b * Nn + n) * Cc + h * Dd + dt * 16 + l16;
                ahi[o] = hi;
                alo[o] = lo;
            }
        }
}

// ---------------------------------------------------------------------------
// Output GEMM (bf16x3 split): out = Ahi@Whi + Ahi@Wlo + Alo@Whi + bias (fp32)
// 64x128 tile -> 512 blocks (2/CU resident).
// ---------------------------------------------------------------------------
__global__ __launch_bounds__(256)
void gemm_out(const short* __restrict__ ahi, const short* __restrict__ alo,
              const short* __restrict__ whi, const short* __restrict__ wlo,
              const float* __restrict__ bias, float* __restrict__ out) {
    __shared__ short smem[24576];      // 48 KB
    short* Ah = smem;                  // 64x64
    short* Al = smem + 4096;
    short* Bh = smem + 8192;           // 128x64
    short* Bl = smem + 16384;

    const int tid = threadIdx.x;
    const int m0 = blockIdx.y * 64;
    const int n0 = blockIdx.x * 128;
    const int wave = tid >> 6, lane = tid & 63;
    const int quad = lane >> 4, l16 = lane & 15;
    const int wm = (wave >> 1) * 32, wn = (wave & 1) * 64;

    floatx4 acc[2][4];
    #pragma unroll
    for (int i = 0; i < 2; i++)
        #pragma unroll
        for (int j = 0; j < 4; j++) acc[i][j] = (floatx4){0.f, 0.f, 0.f, 0.f};

    const short* Ahb = ahi + (size_t)m0 * 512;
    const short* Alb = alo + (size_t)m0 * 512;
    const short* Bhb = whi + (size_t)n0 * 512;
    const short* Blb = wlo + (size_t)n0 * 512;

    for (int k0 = 0; k0 < 512; k0 += 64) {
        __syncthreads();
        stage_tile(Ah, Ahb + k0, 512, tid, 8, 512);
        stage_tile(Al, Alb + k0, 512, tid, 8, 512);
        stage_tile(Bh, Bhb + k0, 512, tid, 8, 1024);
        stage_tile(Bl, Blb + k0, 512, tid, 8, 1024);
        __syncthreads();
        #pragma unroll
        for (int kh = 0; kh < 2; kh++) {
            short8 ah[2], al[2], bh[4], bl[4];
            #pragma unroll
            for (int i = 0; i < 2; i++) {
                ah[i] = fragT(Ah, 8, wm + i * 16 + l16, kh * 4 + quad);
                al[i] = fragT(Al, 8, wm + i * 16 + l16, kh * 4 + quad);
            }
            #pragma unroll
            for (int i = 0; i < 4; i++) {
                bh[i] = fragT(Bh, 8, wn + i * 16 + l16, kh * 4 + quad);
                bl[i] = fragT(Bl, 8, wn + i * 16 + l16, kh * 4 + quad);
            }
            #pragma unroll
            for (int mi = 0; mi < 2; mi++)
                #pragma unroll
                for (int ni = 0; ni < 4; ni++) {
                    acc[mi][ni] = __builtin_amdgcn_mfma_f32_16x16x32_bf16(
                        ah[mi], bh[ni], acc[mi][ni], 0, 0, 0);
                    acc[mi][ni] = __builtin_amdgcn_mfma_f32_16x16x32_bf16(
                        ah[mi], bl[ni], acc[mi][ni], 0, 0, 0);
                    acc[mi][ni] = __builtin_amdgcn_mfma_f32_16x16x32_bf16(
                        al[mi], bh[ni], acc[mi][ni], 0, 0, 0);
                }
        }
    }

    #pragma unroll
    for (int mi = 0; mi < 2; mi++)
        #pragma unroll
        for (int r = 0; r < 4; r++) {
            int m = m0 + wm + mi * 16 + quad * 4 + r;
            #pragma unroll
            for (int ni = 0; ni < 4; ni++) {
                int n = n0 + wn + ni * 16 + l16;
                out[(size_t)m * 512 + n] = acc[mi][ni][r] + bias[n];
            }
        }
}

// ---------------------------------------------------------------------------
extern "C" void kernel_launch(void* const* d_in, const int* in_sizes, int n_in,
                              void* d_out, int out_size, void* d_ws, size_t ws_size,
                              hipStream_t stream) {
    const float* x     = (const float*)d_in[0];
    const float* mask  = (const float*)d_in[1];
    const float* w_qkv = (const float*)d_in[2];
    const float* w_out = (const float*)d_in[3];
    const float* b_out = (const float*)d_in[4];
    float* out = (float*)d_out;

    char* p = (char*)d_ws;
    short* xb  = (short*)p; p += 8388608;      // [8192][512]
    short* wqT = (short*)p; p += 1572864;      // [1536][512]
    short* Ad  = (short*)p; p += 2097152;      // [1024][1024]
    short* whi = (short*)p; p += 524288;       // [512][512]
    short* wlo = (short*)p; p += 524288;
    short* qT  = (short*)p; p += 8388608;      // [b][512][1024]
    short* kT  = (short*)p; p += 8388608;
    short* vT  = (short*)p; p += 8388608;
    short* qd  = (short*)p; p += 8388608;      // [b][1024][512]
    short* kd  = (short*)p; p += 8388608;
    short* ahi = (short*)p; p += 8388608;      // [8192][512]
    short* alo = (short*)p; p += 8388608;

    dim3 blk(256);

    prep_all  <<<2560, blk, 0, stream>>>(x, mask, w_qkv, w_out,
                                         xb, Ad, wqT, whi, wlo);
    gemm_qkv  <<<dim3(12, 64), blk, 0, stream>>>(xb, wqT, qT, kT, vT);
    gemm_diff <<<dim3(4, 8, 16), blk, 0, stream>>>(Ad, qT, kT, qd, kd);
    attn_mfma <<<dim3(8, 64),  blk, 0, stream>>>(qd, kd, vT, mask, ahi, alo);
    gemm_out  <<<dim3(4, 128), blk, 0, stream>>>(ahi, alo, whi, wlo, b_out, out);
}